// Round 1
// baseline (1771.347 us; speedup 1.0000x reference)
//
#include <hip/hip_runtime.h>

#define N_NODES 100000
#define N_EDGES 1600000
#define HDIM 64
#define BN_EPS 1e-5f

// ---- workspace layout (float offsets) ----
#define OFF_DINV   0            // N floats (also used as int degree counts first)
#define OFF_STATS1 100096       // 128 floats: sum[64], sumsq[64]
#define OFF_STATS2 100224       // 4 floats: sum0,sum1,sq0,sq1
#define OFF_SC1    100240       // 64
#define OFF_SH1    100304       // 64
#define OFF_HS1    100416       // N*64
#define OFF_OUT1   6500416      // N*64
#define OFF_HS2    12900416     // N*2
#define OFF_OUT2   13100416     // N*2
// total: 13300416 floats = 53.2 MB

// K0: init degree counts to 1 (self-loop) and zero stat accumulators
__global__ void k0_init(int* __restrict__ deg, float* __restrict__ stats) {
    int i = blockIdx.x * blockDim.x + threadIdx.x;
    if (i < N_NODES) deg[i] = 1;
    if (i < 132) stats[i] = 0.f;   // stats1 (128) + stats2 (4) are contiguous
}

// K1: in-degree histogram
__global__ void k1_degree(const int* __restrict__ dst, int* __restrict__ deg) {
    int e = blockIdx.x * blockDim.x + threadIdx.x;
    if (e < N_EDGES) atomicAdd(&deg[dst[e]], 1);
}

// K2: dinv = rsqrt(deg)  (in place: read int, write float)
__global__ void k2_dinv(float* __restrict__ buf) {
    int i = blockIdx.x * blockDim.x + threadIdx.x;
    if (i < N_NODES) {
        int d = ((const int*)buf)[i];
        buf[i] = rsqrtf((float)d);
    }
}

// K3: h1 = u_S @ w1 ; hs1 = h1*dinv ; out1 = hs1*dinv (self-loop contribution)
__global__ __launch_bounds__(256) void k3_xw1(
        const float* __restrict__ u, const float* __restrict__ w1g,
        const float* __restrict__ dinv, float* __restrict__ hs1,
        float* __restrict__ out1) {
    __shared__ float w[64 * 64];
    __shared__ float rows[4][64];
    int tid = threadIdx.x;
    for (int i = tid; i < 4096; i += 256) w[i] = w1g[i];
    int wv = tid >> 6, c = tid & 63;
    const int ngrp = N_NODES / 4;   // 25000
    for (int g = blockIdx.x; g < ngrp; g += gridDim.x) {
        int r = g * 4 + wv;
        __syncthreads();                       // also covers w staging on first iter
        rows[wv][c] = u[r * 64 + c];
        __syncthreads();
        float acc = 0.f;
#pragma unroll
        for (int k = 0; k < 64; ++k) acc = fmaf(rows[wv][k], w[k * 64 + c], acc);
        float di = dinv[r];
        float h = acc * di;
        hs1[r * 64 + c] = h;
        out1[r * 64 + c] = h * di;
    }
}

// K4: edge scatter layer 1. 16 threads per edge, float4 each.
__global__ __launch_bounds__(256) void k4_scatter1(
        const int* __restrict__ src, const int* __restrict__ dst,
        const float* __restrict__ dinv, const float* __restrict__ hs1,
        float* __restrict__ out1) {
    int idx = blockIdx.x * blockDim.x + threadIdx.x;
    int e = idx >> 4, sub = idx & 15;
    if (e >= N_EDGES) return;
    int s = src[e], d = dst[e];
    float wgt = dinv[d];
    float4 v = ((const float4*)hs1)[s * 16 + sub];
    float* o = out1 + d * 64 + sub * 4;
    unsafeAtomicAdd(o + 0, v.x * wgt);
    unsafeAtomicAdd(o + 1, v.y * wgt);
    unsafeAtomicAdd(o + 2, v.z * wgt);
    unsafeAtomicAdd(o + 3, v.w * wgt);
}

// K5: BN1 column stats (sum, sumsq) over out1
__global__ __launch_bounds__(256) void k5_stats1(
        const float* __restrict__ out1, float* __restrict__ stats) {
    int c = threadIdx.x & 63;
    int wv = threadIdx.x >> 6;
    float s = 0.f, q = 0.f;
    int stride = gridDim.x * 4;
    for (int r = blockIdx.x * 4 + wv; r < N_NODES; r += stride) {
        float x = out1[r * 64 + c];
        s += x;
        q = fmaf(x, x, q);
    }
    __shared__ float ls[4][64], lq[4][64];
    ls[wv][c] = s; lq[wv][c] = q;
    __syncthreads();
    if (threadIdx.x < 64) {
        s = ls[0][c] + ls[1][c] + ls[2][c] + ls[3][c];
        q = lq[0][c] + lq[1][c] + lq[2][c] + lq[3][c];
        unsafeAtomicAdd(&stats[c], s);
        unsafeAtomicAdd(&stats[64 + c], q);
    }
}

// K6: finalize BN1 scale/shift
__global__ void k6_bn1(const float* __restrict__ stats,
                       const float* __restrict__ g1, const float* __restrict__ beta1,
                       float* __restrict__ sc1, float* __restrict__ sh1) {
    int c = threadIdx.x;
    if (c < 64) {
        float invn = 1.f / (float)N_NODES;
        float m = stats[c] * invn;
        float v = stats[64 + c] * invn - m * m;
        float inv = rsqrtf(v + BN_EPS);
        float sc = g1[c] * inv;
        sc1[c] = sc;
        sh1[c] = beta1[c] - m * sc;
    }
}

// K7: s1 = relu(out1*sc1+sh1); h2 = s1@w2; hs2 = h2*dinv; out2 = hs2*dinv
__global__ __launch_bounds__(256) void k7_xw2(
        const float* __restrict__ out1, const float* __restrict__ sc1,
        const float* __restrict__ sh1, const float* __restrict__ w2,
        const float* __restrict__ dinv, float* __restrict__ hs2,
        float* __restrict__ out2) {
    int c = threadIdx.x & 63;
    int wv = threadIdx.x >> 6;
    float s0 = sc1[c], h0 = sh1[c];
    float w20 = w2[c * 2], w21 = w2[c * 2 + 1];
    int stride = gridDim.x * 4;
    for (int r = blockIdx.x * 4 + wv; r < N_NODES; r += stride) {
        float x = out1[r * 64 + c];
        float y = fmaxf(fmaf(x, s0, h0), 0.f);
        float p0 = y * w20, p1 = y * w21;
#pragma unroll
        for (int m = 32; m; m >>= 1) {
            p0 += __shfl_xor(p0, m);
            p1 += __shfl_xor(p1, m);
        }
        if (c == 0) {
            float di = dinv[r];
            float a0 = p0 * di, a1 = p1 * di;
            hs2[r * 2] = a0; hs2[r * 2 + 1] = a1;
            out2[r * 2] = a0 * di; out2[r * 2 + 1] = a1 * di;
        }
    }
}

// K8: edge scatter layer 2 (2 floats per edge)
__global__ __launch_bounds__(256) void k8_scatter2(
        const int* __restrict__ src, const int* __restrict__ dst,
        const float* __restrict__ dinv, const float* __restrict__ hs2,
        float* __restrict__ out2) {
    int e = blockIdx.x * blockDim.x + threadIdx.x;
    if (e >= N_EDGES) return;
    int s = src[e], d = dst[e];
    float wgt = dinv[d];
    float a0 = hs2[s * 2], a1 = hs2[s * 2 + 1];
    unsafeAtomicAdd(&out2[d * 2], a0 * wgt);
    unsafeAtomicAdd(&out2[d * 2 + 1], a1 * wgt);
}

// K9: BN2 stats (2 columns)
__global__ __launch_bounds__(256) void k9_stats2(
        const float* __restrict__ out2, float* __restrict__ stats2) {
    int tid = threadIdx.x;
    float s = 0.f, q = 0.f;
    int stride = gridDim.x * blockDim.x;
    for (int i = blockIdx.x * blockDim.x + tid; i < 2 * N_NODES; i += stride) {
        float x = out2[i];
        s += x;
        q = fmaf(x, x, q);
    }
    __shared__ float ls[256], lq[256];
    ls[tid] = s; lq[tid] = q;
    __syncthreads();
    for (int st = 128; st >= 2; st >>= 1) {
        if (tid < st) { ls[tid] += ls[tid + st]; lq[tid] += lq[tid + st]; }
        __syncthreads();
    }
    if (tid < 2) {
        unsafeAtomicAdd(&stats2[tid], ls[tid]);       // col sums
        unsafeAtomicAdd(&stats2[2 + tid], lq[tid]);   // col sumsq
    }
}

// K10: BN2 + sigmoid + softmax epilogue
__global__ __launch_bounds__(256) void k10_head(
        const float* __restrict__ out2, const float* __restrict__ stats2,
        const float* __restrict__ g2, const float* __restrict__ beta2,
        float* __restrict__ out) {
    int r = blockIdx.x * blockDim.x + threadIdx.x;
    if (r >= N_NODES) return;
    float invn = 1.f / (float)N_NODES;
    float m0 = stats2[0] * invn, m1 = stats2[1] * invn;
    float v0 = stats2[2] * invn - m0 * m0;
    float v1 = stats2[3] * invn - m1 * m1;
    float i0 = rsqrtf(v0 + BN_EPS), i1 = rsqrtf(v1 + BN_EPS);
    float sc0 = g2[0] * i0, sc1 = g2[1] * i1;
    float sh0 = beta2[0] - m0 * sc0, sh1 = beta2[1] - m1 * sc1;
    float x0 = out2[r * 2], x1 = out2[r * 2 + 1];
    float y0 = fmaf(x0, sc0, sh0), y1 = fmaf(x1, sc1, sh1);
    // sigmoid
    out[r * 2] = 1.f / (1.f + __expf(-y0));
    out[r * 2 + 1] = 1.f / (1.f + __expf(-y1));
    // softmax over dim=1 (2 classes)
    out[2 * N_NODES + r * 2] = 1.f / (1.f + __expf(y1 - y0));
    out[2 * N_NODES + r * 2 + 1] = 1.f / (1.f + __expf(y0 - y1));
}

extern "C" void kernel_launch(void* const* d_in, const int* in_sizes, int n_in,
                              void* d_out, int out_size, void* d_ws, size_t ws_size,
                              hipStream_t stream) {
    const int*   edge  = (const int*)d_in[0];          // (2,E): [0,E)=src, [E,2E)=dst
    const float* u_S   = (const float*)d_in[1];
    const float* w1    = (const float*)d_in[2];
    const float* g1    = (const float*)d_in[4];
    const float* beta1 = (const float*)d_in[5];
    const float* w2    = (const float*)d_in[6];
    const float* g2    = (const float*)d_in[8];
    const float* beta2 = (const float*)d_in[9];
    float* out = (float*)d_out;

    float* ws = (float*)d_ws;
    float* dinv   = ws + OFF_DINV;
    float* stats1 = ws + OFF_STATS1;
    float* stats2 = ws + OFF_STATS2;
    float* sc1    = ws + OFF_SC1;
    float* sh1    = ws + OFF_SH1;
    float* hs1    = ws + OFF_HS1;
    float* out1   = ws + OFF_OUT1;
    float* hs2    = ws + OFF_HS2;
    float* out2   = ws + OFF_OUT2;

    const int* src = edge;
    const int* dst = edge + N_EDGES;

    k0_init<<<(N_NODES + 255) / 256, 256, 0, stream>>>((int*)dinv, stats1);
    k1_degree<<<(N_EDGES + 255) / 256, 256, 0, stream>>>(dst, (int*)dinv);
    k2_dinv<<<(N_NODES + 255) / 256, 256, 0, stream>>>(dinv);
    k3_xw1<<<2048, 256, 0, stream>>>(u_S, w1, dinv, hs1, out1);
    k4_scatter1<<<(N_EDGES * 16) / 256, 256, 0, stream>>>(src, dst, dinv, hs1, out1);
    k5_stats1<<<256, 256, 0, stream>>>(out1, stats1);
    k6_bn1<<<1, 64, 0, stream>>>(stats1, g1, beta1, sc1, sh1);
    k7_xw2<<<2048, 256, 0, stream>>>(out1, sc1, sh1, w2, dinv, hs2, out2);
    k8_scatter2<<<(N_EDGES + 255) / 256, 256, 0, stream>>>(src, dst, dinv, hs2, out2);
    k9_stats2<<<256, 256, 0, stream>>>(out2, stats2);
    k10_head<<<(N_NODES + 255) / 256, 256, 0, stream>>>(out2, stats2, g2, beta2, out);
}

// Round 2
// 667.315 us; speedup vs baseline: 2.6544x; 2.6544x over previous
//
#include <hip/hip_runtime.h>

#define N_NODES 100000
#define N_EDGES 1600000
#define BN_EPS 1e-5f

// ---- workspace layout (float/int offsets, 32-bit units) ----
#define OFF_CNT    0            // N ints: in-degree (real edges only)
#define OFF_DINV   100096       // N floats: rsqrt(1+indeg)
#define OFF_OFFS   200192       // N ints: CSR offsets (exclusive scan of cnt)
#define OFF_EBUF   300288       // E ints: src ids bucketed by dst
#define OFF_STATS1 1900288      // 128 floats: sum[64], sumsq[64]
#define OFF_STATS2 1900416      // 4 floats
#define OFF_SC1    1900480      // 64
#define OFF_SH1    1900544      // 64
#define OFF_HS1    1900608      // N*64 floats
#define OFF_OUT1   8300608      // N*64 floats (first N ints also alias as cursor)
#define OFF_HS2    14700608     // N*2
#define OFF_OUT2   14900608     // N*2
// total: 15,100,608 * 4 B = 60.4 MB

// K0: zero degree counts and stat accumulators
__global__ void k0_init(int* __restrict__ cnt, float* __restrict__ stats) {
    int i = blockIdx.x * blockDim.x + threadIdx.x;
    if (i < N_NODES) cnt[i] = 0;
    if (i < 132) stats[i] = 0.f;   // stats1(128)+stats2(4) contiguous
}

// K1: in-degree histogram (real edges)
__global__ void k1_degree(const int* __restrict__ dst, int* __restrict__ cnt) {
    int e = blockIdx.x * blockDim.x + threadIdx.x;
    if (e < N_EDGES) atomicAdd(&cnt[dst[e]], 1);
}

// K2: dinv = rsqrt(1 + indeg)   (self-loop included in degree)
__global__ void k2_dinv(const int* __restrict__ cnt, float* __restrict__ dinv) {
    int i = blockIdx.x * blockDim.x + threadIdx.x;
    if (i < N_NODES) dinv[i] = rsqrtf((float)(1 + cnt[i]));
}

// K3: one-block exclusive scan of cnt -> offs, and cursor copy
__global__ __launch_bounds__(1024) void k_scan(
        const int* __restrict__ cnt, int* __restrict__ offs,
        int* __restrict__ cursor) {
    __shared__ int s[1024];
    int t = threadIdx.x;
    const int CH = (N_NODES + 1023) / 1024;   // 98
    int lo = t * CH, hi = min(lo + CH, N_NODES);
    int sum = 0;
    for (int i = lo; i < hi; ++i) sum += cnt[i];
    s[t] = sum;
    __syncthreads();
    // Hillis-Steele inclusive scan
    for (int off = 1; off < 1024; off <<= 1) {
        int tmp = (t >= off) ? s[t - off] : 0;
        __syncthreads();
        s[t] += tmp;
        __syncthreads();
    }
    int run = s[t] - sum;   // exclusive base for this chunk
    for (int i = lo; i < hi; ++i) {
        offs[i] = run;
        cursor[i] = run;
        run += cnt[i];
    }
}

// K4: bucket edges by dst (CSR build), store src id
__global__ void k_bucket(const int* __restrict__ src, const int* __restrict__ dst,
                         int* __restrict__ cursor, int* __restrict__ ebuf) {
    int e = blockIdx.x * blockDim.x + threadIdx.x;
    if (e >= N_EDGES) return;
    int d = dst[e];
    int pos = atomicAdd(&cursor[d], 1);
    ebuf[pos] = src[e];
}

// K5: hs1 = (u_S @ w1) * dinv[row]
__global__ __launch_bounds__(256) void k3_xw1(
        const float* __restrict__ u, const float* __restrict__ w1g,
        const float* __restrict__ dinv, float* __restrict__ hs1) {
    __shared__ float w[64 * 64];
    __shared__ float rows[4][64];
    int tid = threadIdx.x;
    for (int i = tid; i < 4096; i += 256) w[i] = w1g[i];
    int wv = tid >> 6, c = tid & 63;
    const int ngrp = N_NODES / 4;   // 25000
    for (int g = blockIdx.x; g < ngrp; g += gridDim.x) {
        int r = g * 4 + wv;
        __syncthreads();
        rows[wv][c] = u[r * 64 + c];
        __syncthreads();
        float acc = 0.f;
#pragma unroll
        for (int k = 0; k < 64; ++k) acc = fmaf(rows[wv][k], w[k * 64 + c], acc);
        hs1[r * 64 + c] = acc * dinv[r];
    }
}

// K6: pull aggregation layer 1. 16 threads/node, float4 each.
// out1[d] = (sum_{s in N(d)} hs1[s] + hs1[d]) * dinv[d]
__global__ __launch_bounds__(256) void k_pull1(
        const int* __restrict__ offs, const int* __restrict__ cnt,
        const int* __restrict__ ebuf, const float* __restrict__ dinv,
        const float* __restrict__ hs1, float* __restrict__ out1) {
    int idx = blockIdx.x * blockDim.x + threadIdx.x;
    int d = idx >> 4, sub = idx & 15;
    if (d >= N_NODES) return;
    const float4* h4 = (const float4*)hs1;
    float4 acc = h4[d * 16 + sub];          // self-loop term
    int base = offs[d], c = cnt[d];
    if (c > 0) {
        int s = ebuf[base];
        int j = 0;
        for (; j + 1 < c; ++j) {
            int s2 = ebuf[base + j + 1];    // prefetch next id
            float4 v = h4[s * 16 + sub];
            acc.x += v.x; acc.y += v.y; acc.z += v.z; acc.w += v.w;
            s = s2;
        }
        float4 v = h4[s * 16 + sub];
        acc.x += v.x; acc.y += v.y; acc.z += v.z; acc.w += v.w;
    }
    float di = dinv[d];
    acc.x *= di; acc.y *= di; acc.z *= di; acc.w *= di;
    ((float4*)out1)[d * 16 + sub] = acc;
}

// K7: BN1 column stats
__global__ __launch_bounds__(256) void k5_stats1(
        const float* __restrict__ out1, float* __restrict__ stats) {
    int c = threadIdx.x & 63;
    int wv = threadIdx.x >> 6;
    float s = 0.f, q = 0.f;
    int stride = gridDim.x * 4;
    for (int r = blockIdx.x * 4 + wv; r < N_NODES; r += stride) {
        float x = out1[r * 64 + c];
        s += x;
        q = fmaf(x, x, q);
    }
    __shared__ float ls[4][64], lq[4][64];
    ls[wv][c] = s; lq[wv][c] = q;
    __syncthreads();
    if (threadIdx.x < 64) {
        s = ls[0][c] + ls[1][c] + ls[2][c] + ls[3][c];
        q = lq[0][c] + lq[1][c] + lq[2][c] + lq[3][c];
        unsafeAtomicAdd(&stats[c], s);
        unsafeAtomicAdd(&stats[64 + c], q);
    }
}

// K8: finalize BN1 scale/shift
__global__ void k6_bn1(const float* __restrict__ stats,
                       const float* __restrict__ g1, const float* __restrict__ beta1,
                       float* __restrict__ sc1, float* __restrict__ sh1) {
    int c = threadIdx.x;
    if (c < 64) {
        float invn = 1.f / (float)N_NODES;
        float m = stats[c] * invn;
        float v = stats[64 + c] * invn - m * m;
        float inv = rsqrtf(v + BN_EPS);
        float sc = g1[c] * inv;
        sc1[c] = sc;
        sh1[c] = beta1[c] - m * sc;
    }
}

// K9: s1 = relu(bn1(out1)); hs2 = (s1 @ w2) * dinv[row]
__global__ __launch_bounds__(256) void k7_xw2(
        const float* __restrict__ out1, const float* __restrict__ sc1,
        const float* __restrict__ sh1, const float* __restrict__ w2,
        const float* __restrict__ dinv, float* __restrict__ hs2) {
    int c = threadIdx.x & 63;
    int wv = threadIdx.x >> 6;
    float s0 = sc1[c], h0 = sh1[c];
    float w20 = w2[c * 2], w21 = w2[c * 2 + 1];
    int stride = gridDim.x * 4;
    for (int r = blockIdx.x * 4 + wv; r < N_NODES; r += stride) {
        float x = out1[r * 64 + c];
        float y = fmaxf(fmaf(x, s0, h0), 0.f);
        float p0 = y * w20, p1 = y * w21;
#pragma unroll
        for (int m = 32; m; m >>= 1) {
            p0 += __shfl_xor(p0, m);
            p1 += __shfl_xor(p1, m);
        }
        if (c == 0) {
            float di = dinv[r];
            hs2[r * 2] = p0 * di;
            hs2[r * 2 + 1] = p1 * di;
        }
    }
}

// K10: pull aggregation layer 2 (2 floats/node, 1 thread/node)
__global__ __launch_bounds__(256) void k_pull2(
        const int* __restrict__ offs, const int* __restrict__ cnt,
        const int* __restrict__ ebuf, const float* __restrict__ dinv,
        const float* __restrict__ hs2, float* __restrict__ out2) {
    int d = blockIdx.x * blockDim.x + threadIdx.x;
    if (d >= N_NODES) return;
    const float2* h2 = (const float2*)hs2;
    float2 self = h2[d];
    float a0 = self.x, a1 = self.y;
    int base = offs[d], c = cnt[d];
    for (int j = 0; j < c; ++j) {
        int s = ebuf[base + j];
        float2 v = h2[s];
        a0 += v.x; a1 += v.y;
    }
    float di = dinv[d];
    ((float2*)out2)[d] = make_float2(a0 * di, a1 * di);
}

// K11: BN2 stats (2 columns)
__global__ __launch_bounds__(256) void k9_stats2(
        const float* __restrict__ out2, float* __restrict__ stats2) {
    int tid = threadIdx.x;
    float s = 0.f, q = 0.f;
    int stride = gridDim.x * blockDim.x;
    for (int i = blockIdx.x * blockDim.x + tid; i < 2 * N_NODES; i += stride) {
        float x = out2[i];
        s += x;
        q = fmaf(x, x, q);
    }
    __shared__ float ls[256], lq[256];
    ls[tid] = s; lq[tid] = q;
    __syncthreads();
    for (int st = 128; st >= 2; st >>= 1) {
        if (tid < st) { ls[tid] += ls[tid + st]; lq[tid] += lq[tid + st]; }
        __syncthreads();
    }
    if (tid < 2) {
        unsafeAtomicAdd(&stats2[tid], ls[tid]);
        unsafeAtomicAdd(&stats2[2 + tid], lq[tid]);
    }
}

// K12: BN2 + sigmoid + softmax epilogue
__global__ __launch_bounds__(256) void k10_head(
        const float* __restrict__ out2, const float* __restrict__ stats2,
        const float* __restrict__ g2, const float* __restrict__ beta2,
        float* __restrict__ out) {
    int r = blockIdx.x * blockDim.x + threadIdx.x;
    if (r >= N_NODES) return;
    float invn = 1.f / (float)N_NODES;
    float m0 = stats2[0] * invn, m1 = stats2[1] * invn;
    float v0 = stats2[2] * invn - m0 * m0;
    float v1 = stats2[3] * invn - m1 * m1;
    float i0 = rsqrtf(v0 + BN_EPS), i1 = rsqrtf(v1 + BN_EPS);
    float sc0 = g2[0] * i0, sc1 = g2[1] * i1;
    float sh0 = beta2[0] - m0 * sc0, sh1 = beta2[1] - m1 * sc1;
    float x0 = out2[r * 2], x1 = out2[r * 2 + 1];
    float y0 = fmaf(x0, sc0, sh0), y1 = fmaf(x1, sc1, sh1);
    out[r * 2] = 1.f / (1.f + __expf(-y0));
    out[r * 2 + 1] = 1.f / (1.f + __expf(-y1));
    out[2 * N_NODES + r * 2] = 1.f / (1.f + __expf(y1 - y0));
    out[2 * N_NODES + r * 2 + 1] = 1.f / (1.f + __expf(y0 - y1));
}

extern "C" void kernel_launch(void* const* d_in, const int* in_sizes, int n_in,
                              void* d_out, int out_size, void* d_ws, size_t ws_size,
                              hipStream_t stream) {
    const int*   edge  = (const int*)d_in[0];          // (2,E): [0,E)=src, [E,2E)=dst
    const float* u_S   = (const float*)d_in[1];
    const float* w1    = (const float*)d_in[2];
    const float* g1    = (const float*)d_in[4];
    const float* beta1 = (const float*)d_in[5];
    const float* w2    = (const float*)d_in[6];
    const float* g2    = (const float*)d_in[8];
    const float* beta2 = (const float*)d_in[9];
    float* out = (float*)d_out;

    float* ws = (float*)d_ws;
    int*   cnt    = (int*)(ws + OFF_CNT);
    float* dinv   = ws + OFF_DINV;
    int*   offs   = (int*)(ws + OFF_OFFS);
    int*   ebuf   = (int*)(ws + OFF_EBUF);
    float* stats1 = ws + OFF_STATS1;
    float* stats2 = ws + OFF_STATS2;
    float* sc1    = ws + OFF_SC1;
    float* sh1    = ws + OFF_SH1;
    float* hs1    = ws + OFF_HS1;
    float* out1   = ws + OFF_OUT1;
    int*   cursor = (int*)(ws + OFF_OUT1);   // alias: dead before k_pull1 writes out1
    float* hs2    = ws + OFF_HS2;
    float* out2   = ws + OFF_OUT2;

    const int* src = edge;
    const int* dst = edge + N_EDGES;

    k0_init<<<(N_NODES + 255) / 256, 256, 0, stream>>>(cnt, stats1);
    k1_degree<<<(N_EDGES + 255) / 256, 256, 0, stream>>>(dst, cnt);
    k2_dinv<<<(N_NODES + 255) / 256, 256, 0, stream>>>(cnt, dinv);
    k_scan<<<1, 1024, 0, stream>>>(cnt, offs, cursor);
    k_bucket<<<(N_EDGES + 255) / 256, 256, 0, stream>>>(src, dst, cursor, ebuf);
    k3_xw1<<<2048, 256, 0, stream>>>(u_S, w1, dinv, hs1);
    k_pull1<<<(N_NODES * 16 + 255) / 256, 256, 0, stream>>>(offs, cnt, ebuf, dinv, hs1, out1);
    k5_stats1<<<256, 256, 0, stream>>>(out1, stats1);
    k6_bn1<<<1, 64, 0, stream>>>(stats1, g1, beta1, sc1, sh1);
    k7_xw2<<<2048, 256, 0, stream>>>(out1, sc1, sh1, w2, dinv, hs2);
    k_pull2<<<(N_NODES + 255) / 256, 256, 0, stream>>>(offs, cnt, ebuf, dinv, hs2, out2);
    k9_stats2<<<256, 256, 0, stream>>>(out2, stats2);
    k10_head<<<(N_NODES + 255) / 256, 256, 0, stream>>>(out2, stats2, g2, beta2, out);
}

// Round 3
// 459.142 us; speedup vs baseline: 3.8579x; 1.4534x over previous
//
#include <hip/hip_runtime.h>

#define N_NODES 100000
#define N_EDGES 1600000
#define BN_EPS 1e-5f
#define SCAN_NBLK 98   // ceil(100000/1024)

// ---- workspace layout (float/int offsets, 32-bit units) ----
#define OFF_CNT    0            // N ints: in-degree (real edges only)
#define OFF_DINV   100096       // N floats: rsqrt(1+indeg)
#define OFF_OFFS   200192       // N ints: CSR offsets (exclusive scan of cnt)
#define OFF_EBUF   300288       // E ints: src ids bucketed by dst
#define OFF_STATS1 1900288      // 128 floats: sum[64], sumsq[64]
#define OFF_STATS2 1900416      // 4 floats
#define OFF_SC1    1900480      // 64
#define OFF_SH1    1900544      // 64
#define OFF_HS1    1900608      // N*64 floats
#define OFF_OUT1   8300608      // N*64 floats (head also aliases cursor/bsum/bbase pre-pull)
#define OFF_HS2    14700608     // N*2
#define OFF_OUT2   14900608     // N*2
// aliases inside OUT1 (dead before k_pull1 writes out1):
#define OFF_CURSOR OFF_OUT1               // N ints
#define OFF_BSUM   (OFF_OUT1 + 100096)    // 128 ints
#define OFF_BBASE  (OFF_OUT1 + 100224)    // 128 ints

// K0: zero degree counts and stat accumulators
__global__ void k0_init(int* __restrict__ cnt, float* __restrict__ stats) {
    int i = blockIdx.x * blockDim.x + threadIdx.x;
    if (i < N_NODES) cnt[i] = 0;
    if (i < 132) stats[i] = 0.f;   // stats1(128)+stats2(4) contiguous
}

// K1: in-degree histogram (real edges)
__global__ void k1_degree(const int* __restrict__ dst, int* __restrict__ cnt) {
    int e = blockIdx.x * blockDim.x + threadIdx.x;
    if (e < N_EDGES) atomicAdd(&cnt[dst[e]], 1);
}

// Scan phase A: per-block sums of cnt (1024 elems/block); fused dinv compute
__global__ __launch_bounds__(256) void k_scan_a(
        const int* __restrict__ cnt, int* __restrict__ bsum,
        float* __restrict__ dinv) {
    int b = blockIdx.x, t = threadIdx.x;
    int base = b * 1024 + t * 4;
    int s = 0;
#pragma unroll
    for (int i = 0; i < 4; ++i) {
        int idx = base + i;
        if (idx < N_NODES) {
            int c = cnt[idx];
            s += c;
            dinv[idx] = rsqrtf((float)(1 + c));
        }
    }
#pragma unroll
    for (int off = 32; off; off >>= 1) s += __shfl_down(s, off);
    __shared__ int wsum[4];
    if ((t & 63) == 0) wsum[t >> 6] = s;
    __syncthreads();
    if (t == 0) bsum[b] = wsum[0] + wsum[1] + wsum[2] + wsum[3];
}

// Scan phase B: one tiny block scans the 98 block sums -> exclusive bases
__global__ __launch_bounds__(128) void k_scan_b(
        const int* __restrict__ bsum, int* __restrict__ bbase) {
    __shared__ int s[128];
    int t = threadIdx.x;
    int v = (t < SCAN_NBLK) ? bsum[t] : 0;
    s[t] = v;
    __syncthreads();
    for (int off = 1; off < 128; off <<= 1) {
        int tmp = (t >= off) ? s[t - off] : 0;
        __syncthreads();
        s[t] += tmp;
        __syncthreads();
    }
    if (t < SCAN_NBLK) bbase[t] = s[t] - v;   // exclusive
}

// Scan phase C: per-block exclusive scan + base -> offs, cursor
__global__ __launch_bounds__(256) void k_scan_c(
        const int* __restrict__ cnt, const int* __restrict__ bbase,
        int* __restrict__ offs, int* __restrict__ cursor) {
    int b = blockIdx.x, t = threadIdx.x;
    int lane = t & 63, wv = t >> 6;
    int base = b * 1024 + t * 4;
    int c[4];
    int ts = 0;
#pragma unroll
    for (int i = 0; i < 4; ++i) {
        int idx = base + i;
        c[i] = (idx < N_NODES) ? cnt[idx] : 0;
        ts += c[i];
    }
    int inc = ts;   // wave inclusive scan
#pragma unroll
    for (int off = 1; off < 64; off <<= 1) {
        int n = __shfl_up(inc, off);
        if (lane >= off) inc += n;
    }
    __shared__ int wsum[4];
    if (lane == 63) wsum[wv] = inc;
    __syncthreads();
    int wbase = 0;
    for (int i = 0; i < wv; ++i) wbase += wsum[i];
    int run = bbase[b] + wbase + (inc - ts);
#pragma unroll
    for (int i = 0; i < 4; ++i) {
        int idx = base + i;
        if (idx < N_NODES) { offs[idx] = run; cursor[idx] = run; }
        run += c[i];
    }
}

// K4: bucket edges by dst (CSR build), store src id
__global__ void k_bucket(const int* __restrict__ src, const int* __restrict__ dst,
                         int* __restrict__ cursor, int* __restrict__ ebuf) {
    int e = blockIdx.x * blockDim.x + threadIdx.x;
    if (e >= N_EDGES) return;
    int d = dst[e];
    int pos = atomicAdd(&cursor[d], 1);
    ebuf[pos] = src[e];
}

// K5: hs1 = (u_S @ w1) * dinv[row]
__global__ __launch_bounds__(256) void k3_xw1(
        const float* __restrict__ u, const float* __restrict__ w1g,
        const float* __restrict__ dinv, float* __restrict__ hs1) {
    __shared__ float w[64 * 64];
    __shared__ float rows[4][64];
    int tid = threadIdx.x;
    for (int i = tid; i < 4096; i += 256) w[i] = w1g[i];
    int wv = tid >> 6, c = tid & 63;
    const int ngrp = N_NODES / 4;   // 25000
    for (int g = blockIdx.x; g < ngrp; g += gridDim.x) {
        int r = g * 4 + wv;
        __syncthreads();
        rows[wv][c] = u[r * 64 + c];
        __syncthreads();
        float acc = 0.f;
#pragma unroll
        for (int k = 0; k < 64; ++k) acc = fmaf(rows[wv][k], w[k * 64 + c], acc);
        hs1[r * 64 + c] = acc * dinv[r];
    }
}

// K6: pull aggregation layer 1. 16 threads/node, float4 each.
__global__ __launch_bounds__(256) void k_pull1(
        const int* __restrict__ offs, const int* __restrict__ cnt,
        const int* __restrict__ ebuf, const float* __restrict__ dinv,
        const float* __restrict__ hs1, float* __restrict__ out1) {
    int idx = blockIdx.x * blockDim.x + threadIdx.x;
    int d = idx >> 4, sub = idx & 15;
    if (d >= N_NODES) return;
    const float4* h4 = (const float4*)hs1;
    float4 acc = h4[d * 16 + sub];          // self-loop term
    int base = offs[d], c = cnt[d];
    if (c > 0) {
        int s = ebuf[base];
        int j = 0;
        for (; j + 1 < c; ++j) {
            int s2 = ebuf[base + j + 1];    // prefetch next id
            float4 v = h4[s * 16 + sub];
            acc.x += v.x; acc.y += v.y; acc.z += v.z; acc.w += v.w;
            s = s2;
        }
        float4 v = h4[s * 16 + sub];
        acc.x += v.x; acc.y += v.y; acc.z += v.z; acc.w += v.w;
    }
    float di = dinv[d];
    acc.x *= di; acc.y *= di; acc.z *= di; acc.w *= di;
    ((float4*)out1)[d * 16 + sub] = acc;
}

// K7: BN1 column stats
__global__ __launch_bounds__(256) void k5_stats1(
        const float* __restrict__ out1, float* __restrict__ stats) {
    int c = threadIdx.x & 63;
    int wv = threadIdx.x >> 6;
    float s = 0.f, q = 0.f;
    int stride = gridDim.x * 4;
    for (int r = blockIdx.x * 4 + wv; r < N_NODES; r += stride) {
        float x = out1[r * 64 + c];
        s += x;
        q = fmaf(x, x, q);
    }
    __shared__ float ls[4][64], lq[4][64];
    ls[wv][c] = s; lq[wv][c] = q;
    __syncthreads();
    if (threadIdx.x < 64) {
        s = ls[0][c] + ls[1][c] + ls[2][c] + ls[3][c];
        q = lq[0][c] + lq[1][c] + lq[2][c] + lq[3][c];
        unsafeAtomicAdd(&stats[c], s);
        unsafeAtomicAdd(&stats[64 + c], q);
    }
}

// K8: finalize BN1 scale/shift
__global__ void k6_bn1(const float* __restrict__ stats,
                       const float* __restrict__ g1, const float* __restrict__ beta1,
                       float* __restrict__ sc1, float* __restrict__ sh1) {
    int c = threadIdx.x;
    if (c < 64) {
        float invn = 1.f / (float)N_NODES;
        float m = stats[c] * invn;
        float v = stats[64 + c] * invn - m * m;
        float inv = rsqrtf(v + BN_EPS);
        float sc = g1[c] * inv;
        sc1[c] = sc;
        sh1[c] = beta1[c] - m * sc;
    }
}

// K9: s1 = relu(bn1(out1)); hs2 = (s1 @ w2) * dinv[row]
__global__ __launch_bounds__(256) void k7_xw2(
        const float* __restrict__ out1, const float* __restrict__ sc1,
        const float* __restrict__ sh1, const float* __restrict__ w2,
        const float* __restrict__ dinv, float* __restrict__ hs2) {
    int c = threadIdx.x & 63;
    int wv = threadIdx.x >> 6;
    float s0 = sc1[c], h0 = sh1[c];
    float w20 = w2[c * 2], w21 = w2[c * 2 + 1];
    int stride = gridDim.x * 4;
    for (int r = blockIdx.x * 4 + wv; r < N_NODES; r += stride) {
        float x = out1[r * 64 + c];
        float y = fmaxf(fmaf(x, s0, h0), 0.f);
        float p0 = y * w20, p1 = y * w21;
#pragma unroll
        for (int m = 32; m; m >>= 1) {
            p0 += __shfl_xor(p0, m);
            p1 += __shfl_xor(p1, m);
        }
        if (c == 0) {
            float di = dinv[r];
            hs2[r * 2] = p0 * di;
            hs2[r * 2 + 1] = p1 * di;
        }
    }
}

// K10: pull aggregation layer 2 (2 floats/node, 1 thread/node)
__global__ __launch_bounds__(256) void k_pull2(
        const int* __restrict__ offs, const int* __restrict__ cnt,
        const int* __restrict__ ebuf, const float* __restrict__ dinv,
        const float* __restrict__ hs2, float* __restrict__ out2) {
    int d = blockIdx.x * blockDim.x + threadIdx.x;
    if (d >= N_NODES) return;
    const float2* h2 = (const float2*)hs2;
    float2 self = h2[d];
    float a0 = self.x, a1 = self.y;
    int base = offs[d], c = cnt[d];
    for (int j = 0; j < c; ++j) {
        int s = ebuf[base + j];
        float2 v = h2[s];
        a0 += v.x; a1 += v.y;
    }
    float di = dinv[d];
    ((float2*)out2)[d] = make_float2(a0 * di, a1 * di);
}

// K11: BN2 stats (2 columns)
__global__ __launch_bounds__(256) void k9_stats2(
        const float* __restrict__ out2, float* __restrict__ stats2) {
    int tid = threadIdx.x;
    float s = 0.f, q = 0.f;
    int stride = gridDim.x * blockDim.x;
    for (int i = blockIdx.x * blockDim.x + tid; i < 2 * N_NODES; i += stride) {
        float x = out2[i];
        s += x;
        q = fmaf(x, x, q);
    }
    __shared__ float ls[256], lq[256];
    ls[tid] = s; lq[tid] = q;
    __syncthreads();
    for (int st = 128; st >= 2; st >>= 1) {
        if (tid < st) { ls[tid] += ls[tid + st]; lq[tid] += lq[tid + st]; }
        __syncthreads();
    }
    if (tid < 2) {
        unsafeAtomicAdd(&stats2[tid], ls[tid]);
        unsafeAtomicAdd(&stats2[2 + tid], lq[tid]);
    }
}

// K12: BN2 + sigmoid + softmax epilogue
__global__ __launch_bounds__(256) void k10_head(
        const float* __restrict__ out2, const float* __restrict__ stats2,
        const float* __restrict__ g2, const float* __restrict__ beta2,
        float* __restrict__ out) {
    int r = blockIdx.x * blockDim.x + threadIdx.x;
    if (r >= N_NODES) return;
    float invn = 1.f / (float)N_NODES;
    float m0 = stats2[0] * invn, m1 = stats2[1] * invn;
    float v0 = stats2[2] * invn - m0 * m0;
    float v1 = stats2[3] * invn - m1 * m1;
    float i0 = rsqrtf(v0 + BN_EPS), i1 = rsqrtf(v1 + BN_EPS);
    float sc0 = g2[0] * i0, sc1 = g2[1] * i1;
    float sh0 = beta2[0] - m0 * sc0, sh1 = beta2[1] - m1 * sc1;
    float x0 = out2[r * 2], x1 = out2[r * 2 + 1];
    float y0 = fmaf(x0, sc0, sh0), y1 = fmaf(x1, sc1, sh1);
    out[r * 2] = 1.f / (1.f + __expf(-y0));
    out[r * 2 + 1] = 1.f / (1.f + __expf(-y1));
    out[2 * N_NODES + r * 2] = 1.f / (1.f + __expf(y1 - y0));
    out[2 * N_NODES + r * 2 + 1] = 1.f / (1.f + __expf(y0 - y1));
}

extern "C" void kernel_launch(void* const* d_in, const int* in_sizes, int n_in,
                              void* d_out, int out_size, void* d_ws, size_t ws_size,
                              hipStream_t stream) {
    const int*   edge  = (const int*)d_in[0];          // (2,E): [0,E)=src, [E,2E)=dst
    const float* u_S   = (const float*)d_in[1];
    const float* w1    = (const float*)d_in[2];
    const float* g1    = (const float*)d_in[4];
    const float* beta1 = (const float*)d_in[5];
    const float* w2    = (const float*)d_in[6];
    const float* g2    = (const float*)d_in[8];
    const float* beta2 = (const float*)d_in[9];
    float* out = (float*)d_out;

    float* ws = (float*)d_ws;
    int*   cnt    = (int*)(ws + OFF_CNT);
    float* dinv   = ws + OFF_DINV;
    int*   offs   = (int*)(ws + OFF_OFFS);
    int*   ebuf   = (int*)(ws + OFF_EBUF);
    float* stats1 = ws + OFF_STATS1;
    float* stats2 = ws + OFF_STATS2;
    float* sc1    = ws + OFF_SC1;
    float* sh1    = ws + OFF_SH1;
    float* hs1    = ws + OFF_HS1;
    float* out1   = ws + OFF_OUT1;
    int*   cursor = (int*)(ws + OFF_CURSOR);   // alias: dead before k_pull1 writes out1
    int*   bsum   = (int*)(ws + OFF_BSUM);
    int*   bbase  = (int*)(ws + OFF_BBASE);
    float* hs2    = ws + OFF_HS2;
    float* out2   = ws + OFF_OUT2;

    const int* src = edge;
    const int* dst = edge + N_EDGES;

    k0_init<<<(N_NODES + 255) / 256, 256, 0, stream>>>(cnt, stats1);
    k1_degree<<<(N_EDGES + 255) / 256, 256, 0, stream>>>(dst, cnt);
    k_scan_a<<<SCAN_NBLK, 256, 0, stream>>>(cnt, bsum, dinv);
    k_scan_b<<<1, 128, 0, stream>>>(bsum, bbase);
    k_scan_c<<<SCAN_NBLK, 256, 0, stream>>>(cnt, bbase, offs, cursor);
    k_bucket<<<(N_EDGES + 255) / 256, 256, 0, stream>>>(src, dst, cursor, ebuf);
    k3_xw1<<<2048, 256, 0, stream>>>(u_S, w1, dinv, hs1);
    k_pull1<<<(N_NODES * 16 + 255) / 256, 256, 0, stream>>>(offs, cnt, ebuf, dinv, hs1, out1);
    k5_stats1<<<256, 256, 0, stream>>>(out1, stats1);
    k6_bn1<<<1, 64, 0, stream>>>(stats1, g1, beta1, sc1, sh1);
    k7_xw2<<<2048, 256, 0, stream>>>(out1, sc1, sh1, w2, dinv, hs2);
    k_pull2<<<(N_NODES + 255) / 256, 256, 0, stream>>>(offs, cnt, ebuf, dinv, hs2, out2);
    k9_stats2<<<256, 256, 0, stream>>>(out2, stats2);
    k10_head<<<(N_NODES + 255) / 256, 256, 0, stream>>>(out2, stats2, g2, beta2, out);
}

// Round 4
// 309.339 us; speedup vs baseline: 5.7262x; 1.4843x over previous
//
#include <hip/hip_runtime.h>

#define N_NODES 100000
#define N_EDGES 1600000
#define BN_EPS 1e-5f

#define NBUCK 256          // dst buckets
#define NPB   391          // nodes per bucket (ceil(100000/256)); last has 295
#define BCAP  8192         // edge capacity per bucket (mean 6250, sigma ~79)
#define EPB_BIN 4096       // edges per k_bin block
#define NBLK_BIN ((N_EDGES + EPB_BIN - 1) / EPB_BIN)   // 391

// ---- workspace layout (32-bit units) ----
#define OFF_GCUR   0            // 256 ints: bucket fill cursors (into binned)
#define OFF_CNT    256          // N ints
#define OFF_DINV   100352       // N floats
#define OFF_OFFS   200448       // N ints (gapped CSR offsets into ebuf)
#define OFF_EBUF   300544       // NBUCK*BCAP = 2,097,152 ints (gapped)
#define OFF_STATS1 2397696      // 128 floats
#define OFF_STATS2 2397824      // 4 floats
#define OFF_SC1    2397888      // 64
#define OFF_SH1    2397952      // 64
#define OFF_HS1    2398016      // N*64 floats  (head aliases binned int2[2M] pre-k3)
#define OFF_BINNED OFF_HS1      // int2[NBUCK*BCAP] = 4,194,304 ints < 6,400,000
#define OFF_OUT1   8798016      // N*64 floats
#define OFF_HS2    15198016     // N*2
#define OFF_OUT2   15398016     // N*2
// total 15,598,016 * 4B = 62.4 MB

// K0: init bucket cursors to slice bases; zero stat accumulators
__global__ __launch_bounds__(256) void k0_init(int* __restrict__ gcur,
                                               float* __restrict__ stats) {
    int t = threadIdx.x;
    gcur[t] = t * BCAP;
    if (t < 132) stats[t] = 0.f;   // stats1(128)+stats2(4) contiguous
}

// K1: radix partition edges into 256 dst-buckets.
__global__ __launch_bounds__(256) void k_bin(
        const int* __restrict__ src, const int* __restrict__ dst,
        int* __restrict__ gcur, int2* __restrict__ binned) {
    __shared__ int hist[NBUCK];
    __shared__ int lcur[NBUCK];
    int t = threadIdx.x, b = blockIdx.x;
    hist[t] = 0;
    __syncthreads();
    int e0 = b * EPB_BIN;
    int sreg[16], dreg[16];
#pragma unroll
    for (int i = 0; i < 16; ++i) {
        int e = e0 + t + i * 256;              // coalesced
        if (e < N_EDGES) {
            sreg[i] = src[e];
            dreg[i] = dst[e];
            atomicAdd(&hist[dreg[i] / NPB], 1);
        } else dreg[i] = -1;
    }
    __syncthreads();
    int h = hist[t];
    lcur[t] = (h > 0) ? atomicAdd(&gcur[t], h) : 0;   // reserve contiguous run
    __syncthreads();
#pragma unroll
    for (int i = 0; i < 16; ++i) {
        if (dreg[i] >= 0) {
            int bk = dreg[i] / NPB;
            int pos = atomicAdd(&lcur[bk], 1);
            if (pos < (bk + 1) * BCAP)          // overflow guard (never taken)
                binned[pos] = make_int2(sreg[i], dreg[i]);
        }
    }
}

// K2: per-bucket CSR build (LDS-only histogram/scan/cursors) + dinv.
__global__ __launch_bounds__(256) void k_csr(
        const int* __restrict__ gcur, const int2* __restrict__ binned,
        int* __restrict__ cnt, float* __restrict__ dinv,
        int* __restrict__ offs, int* __restrict__ ebuf) {
    int b = blockIdx.x, t = threadIdx.x;
    int nb0 = b * NPB;
    int nn = min(NPB, N_NODES - nb0);          // 391 (or 295 for last)
    __shared__ int lcnt[NPB];
    __shared__ int lcur[NPB];
    __shared__ int sc[512];
    for (int i = t; i < NPB; i += 256) lcnt[i] = 0;
    __syncthreads();
    int base = b * BCAP;
    int m = min(gcur[b] - base, BCAP);
    for (int j = t; j < m; j += 256)
        atomicAdd(&lcnt[binned[base + j].y - nb0], 1);
    __syncthreads();
    // exclusive scan of lcnt[0..NPB) via Hillis-Steele over 512 slots
    sc[t] = (t < NPB) ? lcnt[t] : 0;
    sc[256 + t] = (256 + t < NPB) ? lcnt[256 + t] : 0;
    __syncthreads();
    for (int off = 1; off < 512; off <<= 1) {
        int v0 = (t >= off) ? sc[t - off] : 0;
        int i1 = t + 256;
        int v1 = (i1 >= off) ? sc[i1 - off] : 0;
        __syncthreads();
        sc[t] += v0; sc[i1] += v1;
        __syncthreads();
    }
    for (int i = t; i < nn; i += 256) {
        int c = lcnt[i];
        int excl = sc[i] - c;
        lcur[i] = excl;
        offs[nb0 + i] = base + excl;           // gapped global CSR offset
        cnt[nb0 + i] = c;
        dinv[nb0 + i] = rsqrtf((float)(1 + c));
    }
    __syncthreads();
    for (int j = t; j < m; j += 256) {
        int2 p = binned[base + j];
        int pos = atomicAdd(&lcur[p.y - nb0], 1);
        ebuf[base + pos] = p.x;                // confined to 32KB slice
    }
}

// K3: hs1 = (u_S @ w1) * dinv[row]
__global__ __launch_bounds__(256) void k3_xw1(
        const float* __restrict__ u, const float* __restrict__ w1g,
        const float* __restrict__ dinv, float* __restrict__ hs1) {
    __shared__ float w[64 * 64];
    __shared__ float rows[4][64];
    int tid = threadIdx.x;
    for (int i = tid; i < 4096; i += 256) w[i] = w1g[i];
    int wv = tid >> 6, c = tid & 63;
    const int ngrp = N_NODES / 4;   // 25000
    for (int g = blockIdx.x; g < ngrp; g += gridDim.x) {
        int r = g * 4 + wv;
        __syncthreads();
        rows[wv][c] = u[r * 64 + c];
        __syncthreads();
        float acc = 0.f;
#pragma unroll
        for (int k = 0; k < 64; ++k) acc = fmaf(rows[wv][k], w[k * 64 + c], acc);
        hs1[r * 64 + c] = acc * dinv[r];
    }
}

// K4: pull aggregation layer 1. 16 threads/node, float4 each.
__global__ __launch_bounds__(256) void k_pull1(
        const int* __restrict__ offs, const int* __restrict__ cnt,
        const int* __restrict__ ebuf, const float* __restrict__ dinv,
        const float* __restrict__ hs1, float* __restrict__ out1) {
    int idx = blockIdx.x * blockDim.x + threadIdx.x;
    int d = idx >> 4, sub = idx & 15;
    if (d >= N_NODES) return;
    const float4* h4 = (const float4*)hs1;
    float4 acc = h4[d * 16 + sub];          // self-loop term
    int base = offs[d], c = cnt[d];
    if (c > 0) {
        int s = ebuf[base];
        int j = 0;
        for (; j + 1 < c; ++j) {
            int s2 = ebuf[base + j + 1];    // prefetch next id
            float4 v = h4[s * 16 + sub];
            acc.x += v.x; acc.y += v.y; acc.z += v.z; acc.w += v.w;
            s = s2;
        }
        float4 v = h4[s * 16 + sub];
        acc.x += v.x; acc.y += v.y; acc.z += v.z; acc.w += v.w;
    }
    float di = dinv[d];
    acc.x *= di; acc.y *= di; acc.z *= di; acc.w *= di;
    ((float4*)out1)[d * 16 + sub] = acc;
}

// K5: BN1 column stats
__global__ __launch_bounds__(256) void k5_stats1(
        const float* __restrict__ out1, float* __restrict__ stats) {
    int c = threadIdx.x & 63;
    int wv = threadIdx.x >> 6;
    float s = 0.f, q = 0.f;
    int stride = gridDim.x * 4;
    for (int r = blockIdx.x * 4 + wv; r < N_NODES; r += stride) {
        float x = out1[r * 64 + c];
        s += x;
        q = fmaf(x, x, q);
    }
    __shared__ float ls[4][64], lq[4][64];
    ls[wv][c] = s; lq[wv][c] = q;
    __syncthreads();
    if (threadIdx.x < 64) {
        s = ls[0][c] + ls[1][c] + ls[2][c] + ls[3][c];
        q = lq[0][c] + lq[1][c] + lq[2][c] + lq[3][c];
        unsafeAtomicAdd(&stats[c], s);
        unsafeAtomicAdd(&stats[64 + c], q);
    }
}

// K6: finalize BN1 scale/shift
__global__ void k6_bn1(const float* __restrict__ stats,
                       const float* __restrict__ g1, const float* __restrict__ beta1,
                       float* __restrict__ sc1, float* __restrict__ sh1) {
    int c = threadIdx.x;
    if (c < 64) {
        float invn = 1.f / (float)N_NODES;
        float m = stats[c] * invn;
        float v = stats[64 + c] * invn - m * m;
        float inv = rsqrtf(v + BN_EPS);
        float sc = g1[c] * inv;
        sc1[c] = sc;
        sh1[c] = beta1[c] - m * sc;
    }
}

// K7: s1 = relu(bn1(out1)); hs2 = (s1 @ w2) * dinv[row]
__global__ __launch_bounds__(256) void k7_xw2(
        const float* __restrict__ out1, const float* __restrict__ sc1,
        const float* __restrict__ sh1, const float* __restrict__ w2,
        const float* __restrict__ dinv, float* __restrict__ hs2) {
    int c = threadIdx.x & 63;
    int wv = threadIdx.x >> 6;
    float s0 = sc1[c], h0 = sh1[c];
    float w20 = w2[c * 2], w21 = w2[c * 2 + 1];
    int stride = gridDim.x * 4;
    for (int r = blockIdx.x * 4 + wv; r < N_NODES; r += stride) {
        float x = out1[r * 64 + c];
        float y = fmaxf(fmaf(x, s0, h0), 0.f);
        float p0 = y * w20, p1 = y * w21;
#pragma unroll
        for (int m = 32; m; m >>= 1) {
            p0 += __shfl_xor(p0, m);
            p1 += __shfl_xor(p1, m);
        }
        if (c == 0) {
            float di = dinv[r];
            hs2[r * 2] = p0 * di;
            hs2[r * 2 + 1] = p1 * di;
        }
    }
}

// K8: pull aggregation layer 2 (2 floats/node, 1 thread/node)
__global__ __launch_bounds__(256) void k_pull2(
        const int* __restrict__ offs, const int* __restrict__ cnt,
        const int* __restrict__ ebuf, const float* __restrict__ dinv,
        const float* __restrict__ hs2, float* __restrict__ out2) {
    int d = blockIdx.x * blockDim.x + threadIdx.x;
    if (d >= N_NODES) return;
    const float2* h2 = (const float2*)hs2;
    float2 self = h2[d];
    float a0 = self.x, a1 = self.y;
    int base = offs[d], c = cnt[d];
    for (int j = 0; j < c; ++j) {
        int s = ebuf[base + j];
        float2 v = h2[s];
        a0 += v.x; a1 += v.y;
    }
    float di = dinv[d];
    ((float2*)out2)[d] = make_float2(a0 * di, a1 * di);
}

// K9: BN2 stats (2 columns)
__global__ __launch_bounds__(256) void k9_stats2(
        const float* __restrict__ out2, float* __restrict__ stats2) {
    int tid = threadIdx.x;
    float s = 0.f, q = 0.f;
    int stride = gridDim.x * blockDim.x;
    for (int i = blockIdx.x * blockDim.x + tid; i < 2 * N_NODES; i += stride) {
        float x = out2[i];
        s += x;
        q = fmaf(x, x, q);
    }
    __shared__ float ls[256], lq[256];
    ls[tid] = s; lq[tid] = q;
    __syncthreads();
    for (int st = 128; st >= 2; st >>= 1) {
        if (tid < st) { ls[tid] += ls[tid + st]; lq[tid] += lq[tid + st]; }
        __syncthreads();
    }
    if (tid < 2) {
        unsafeAtomicAdd(&stats2[tid], ls[tid]);
        unsafeAtomicAdd(&stats2[2 + tid], lq[tid]);
    }
}

// K10: BN2 + sigmoid + softmax epilogue
__global__ __launch_bounds__(256) void k10_head(
        const float* __restrict__ out2, const float* __restrict__ stats2,
        const float* __restrict__ g2, const float* __restrict__ beta2,
        float* __restrict__ out) {
    int r = blockIdx.x * blockDim.x + threadIdx.x;
    if (r >= N_NODES) return;
    float invn = 1.f / (float)N_NODES;
    float m0 = stats2[0] * invn, m1 = stats2[1] * invn;
    float v0 = stats2[2] * invn - m0 * m0;
    float v1 = stats2[3] * invn - m1 * m1;
    float i0 = rsqrtf(v0 + BN_EPS), i1 = rsqrtf(v1 + BN_EPS);
    float sc0 = g2[0] * i0, sc1 = g2[1] * i1;
    float sh0 = beta2[0] - m0 * sc0, sh1 = beta2[1] - m1 * sc1;
    float x0 = out2[r * 2], x1 = out2[r * 2 + 1];
    float y0 = fmaf(x0, sc0, sh0), y1 = fmaf(x1, sc1, sh1);
    out[r * 2] = 1.f / (1.f + __expf(-y0));
    out[r * 2 + 1] = 1.f / (1.f + __expf(-y1));
    out[2 * N_NODES + r * 2] = 1.f / (1.f + __expf(y1 - y0));
    out[2 * N_NODES + r * 2 + 1] = 1.f / (1.f + __expf(y0 - y1));
}

extern "C" void kernel_launch(void* const* d_in, const int* in_sizes, int n_in,
                              void* d_out, int out_size, void* d_ws, size_t ws_size,
                              hipStream_t stream) {
    const int*   edge  = (const int*)d_in[0];          // (2,E): [0,E)=src, [E,2E)=dst
    const float* u_S   = (const float*)d_in[1];
    const float* w1    = (const float*)d_in[2];
    const float* g1    = (const float*)d_in[4];
    const float* beta1 = (const float*)d_in[5];
    const float* w2    = (const float*)d_in[6];
    const float* g2    = (const float*)d_in[8];
    const float* beta2 = (const float*)d_in[9];
    float* out = (float*)d_out;

    float* ws = (float*)d_ws;
    int*   gcur   = (int*)(ws + OFF_GCUR);
    int*   cnt    = (int*)(ws + OFF_CNT);
    float* dinv   = ws + OFF_DINV;
    int*   offs   = (int*)(ws + OFF_OFFS);
    int*   ebuf   = (int*)(ws + OFF_EBUF);
    float* stats1 = ws + OFF_STATS1;
    float* stats2 = ws + OFF_STATS2;
    float* sc1    = ws + OFF_SC1;
    float* sh1    = ws + OFF_SH1;
    float* hs1    = ws + OFF_HS1;
    int2*  binned = (int2*)(ws + OFF_BINNED);   // alias of hs1 head; dead before k3_xw1
    float* out1   = ws + OFF_OUT1;
    float* hs2    = ws + OFF_HS2;
    float* out2   = ws + OFF_OUT2;

    const int* src = edge;
    const int* dst = edge + N_EDGES;

    k0_init<<<1, 256, 0, stream>>>(gcur, stats1);
    k_bin<<<NBLK_BIN, 256, 0, stream>>>(src, dst, gcur, binned);
    k_csr<<<NBUCK, 256, 0, stream>>>(gcur, binned, cnt, dinv, offs, ebuf);
    k3_xw1<<<2048, 256, 0, stream>>>(u_S, w1, dinv, hs1);
    k_pull1<<<(N_NODES * 16 + 255) / 256, 256, 0, stream>>>(offs, cnt, ebuf, dinv, hs1, out1);
    k5_stats1<<<256, 256, 0, stream>>>(out1, stats1);
    k6_bn1<<<1, 64, 0, stream>>>(stats1, g1, beta1, sc1, sh1);
    k7_xw2<<<2048, 256, 0, stream>>>(out1, sc1, sh1, w2, dinv, hs2);
    k_pull2<<<(N_NODES + 255) / 256, 256, 0, stream>>>(offs, cnt, ebuf, dinv, hs2, out2);
    k9_stats2<<<256, 256, 0, stream>>>(out2, stats2);
    k10_head<<<(N_NODES + 255) / 256, 256, 0, stream>>>(out2, stats2, g2, beta2, out);
}

// Round 5
// 272.847 us; speedup vs baseline: 6.4921x; 1.1337x over previous
//
#include <hip/hip_runtime.h>
#include <hip/hip_fp16.h>

#define N_NODES 100000
#define N_EDGES 1600000
#define BN_EPS 1e-5f

#define NBUCK 256          // dst buckets
#define NPB   391          // nodes per bucket (ceil(100000/256)); last has 295
#define BCAP  8192         // edge capacity per bucket (mean 6250, ~24 sigma margin)
#define EPB_BIN 4096       // edges per k_bin block
#define NBLK_BIN ((N_EDGES + EPB_BIN - 1) / EPB_BIN)   // 391

// ---- workspace layout (32-bit units) ----
#define OFF_GCUR   0            // 256 ints: bucket fill cursors (into binned)
#define OFF_CNT    256          // N ints
#define OFF_DINV   100352       // N floats
#define OFF_OFFS   200448       // N ints (gapped CSR offsets into ebuf)
#define OFF_EBUF   300544       // NBUCK*BCAP = 2,097,152 ints (gapped)
#define OFF_STATS1 2397696      // 128 floats: sum[64], sumsq[64]
#define OFF_STATS2 2397824      // 4 floats: s0,s1,q0,q1
#define OFF_HS1    2398016      // half[N*64] = 3.2M units (head aliases binned pre-k3)
#define OFF_BINNED OFF_HS1      // int[NBUCK*BCAP] = 2,097,152 < 3,200,000
#define OFF_OUT1   5598016      // half[N*64] = 3.2M units
#define OFF_HS2    8798016      // N*2 floats
#define OFF_OUT2   8998016      // N*2 floats
// total 9,198,016 * 4B = 36.8 MB

__device__ inline float4 cvt4(uint2 v) {
    __half2 a = *(__half2*)&v.x, b = *(__half2*)&v.y;
    float2 fa = __half22float2(a), fb = __half22float2(b);
    return make_float4(fa.x, fa.y, fb.x, fb.y);
}

// K0: init bucket cursors to slice bases; zero stat accumulators
__global__ __launch_bounds__(256) void k0_init(int* __restrict__ gcur,
                                               float* __restrict__ stats) {
    int t = threadIdx.x;
    gcur[t] = t * BCAP;
    if (t < 132) stats[t] = 0.f;   // stats1(128)+stats2(4) contiguous
}

// K1: radix partition edges into 256 dst-buckets; store packed (src | ldst<<17)
__global__ __launch_bounds__(256) void k_bin(
        const int* __restrict__ src, const int* __restrict__ dst,
        int* __restrict__ gcur, int* __restrict__ binned) {
    __shared__ int hist[NBUCK];
    __shared__ int lcur[NBUCK];
    int t = threadIdx.x, b = blockIdx.x;
    hist[t] = 0;
    __syncthreads();
    int e0 = b * EPB_BIN;
    int pkreg[16], bkreg[16];
#pragma unroll
    for (int i = 0; i < 16; ++i) {
        int e = e0 + t + i * 256;              // coalesced
        if (e < N_EDGES) {
            int s = src[e], d = dst[e];
            int bk = d / NPB;
            bkreg[i] = bk;
            pkreg[i] = s | ((d - bk * NPB) << 17);
            atomicAdd(&hist[bk], 1);
        } else bkreg[i] = -1;
    }
    __syncthreads();
    int h = hist[t];
    lcur[t] = (h > 0) ? atomicAdd(&gcur[t], h) : 0;   // reserve contiguous run
    __syncthreads();
#pragma unroll
    for (int i = 0; i < 16; ++i) {
        if (bkreg[i] >= 0) {
            int bk = bkreg[i];
            int pos = atomicAdd(&lcur[bk], 1);
            if (pos < (bk + 1) * BCAP)          // overflow guard (never taken)
                binned[pos] = pkreg[i];
        }
    }
}

// K2: per-bucket CSR build (LDS-only histogram/scan/cursors) + cnt/offs/dinv
__global__ __launch_bounds__(256) void k_csr(
        const int* __restrict__ gcur, const int* __restrict__ binned,
        int* __restrict__ cnt, float* __restrict__ dinv,
        int* __restrict__ offs, int* __restrict__ ebuf) {
    int b = blockIdx.x, t = threadIdx.x;
    int nb0 = b * NPB;
    int nn = min(NPB, N_NODES - nb0);          // 391 (or 295 for last)
    __shared__ int lcnt[NPB];
    __shared__ int lcur[NPB];
    __shared__ int sc[512];
    for (int i = t; i < NPB; i += 256) lcnt[i] = 0;
    __syncthreads();
    int base = b * BCAP;
    int m = min(gcur[b] - base, BCAP);
    for (int j = t; j < m; j += 256)
        atomicAdd(&lcnt[((unsigned)binned[base + j]) >> 17], 1);
    __syncthreads();
    // exclusive scan of lcnt[0..NPB) via Hillis-Steele over 512 slots
    sc[t] = (t < NPB) ? lcnt[t] : 0;
    sc[256 + t] = (256 + t < NPB) ? lcnt[256 + t] : 0;
    __syncthreads();
    for (int off = 1; off < 512; off <<= 1) {
        int v0 = (t >= off) ? sc[t - off] : 0;
        int i1 = t + 256;
        int v1 = (i1 >= off) ? sc[i1 - off] : 0;
        __syncthreads();
        sc[t] += v0; sc[i1] += v1;
        __syncthreads();
    }
    for (int i = t; i < nn; i += 256) {
        int c = lcnt[i];
        int excl = sc[i] - c;
        lcur[i] = excl;
        offs[nb0 + i] = base + excl;           // gapped global CSR offset
        cnt[nb0 + i] = c;
        dinv[nb0 + i] = rsqrtf((float)(1 + c));
    }
    __syncthreads();
    for (int j = t; j < m; j += 256) {
        unsigned v = (unsigned)binned[base + j];
        int pos = atomicAdd(&lcur[v >> 17], 1);
        ebuf[base + pos] = (int)(v & 0x1FFFFu); // confined to 32KB slice
    }
}

// K3: hs1 = fp16( (u_S @ w1) * dinv[row] )
__global__ __launch_bounds__(256) void k3_xw1(
        const float* __restrict__ u, const float* __restrict__ w1g,
        const float* __restrict__ dinv, __half* __restrict__ hs1) {
    __shared__ float w[64 * 64];
    __shared__ float rows[4][64];
    int tid = threadIdx.x;
    for (int i = tid; i < 4096; i += 256) w[i] = w1g[i];
    int wv = tid >> 6, c = tid & 63;
    const int ngrp = N_NODES / 4;   // 25000
    for (int g = blockIdx.x; g < ngrp; g += gridDim.x) {
        int r = g * 4 + wv;
        __syncthreads();
        rows[wv][c] = u[r * 64 + c];
        __syncthreads();
        float acc = 0.f;
#pragma unroll
        for (int k = 0; k < 64; ++k) acc = fmaf(rows[wv][k], w[k * 64 + c], acc);
        hs1[r * 64 + c] = __float2half(acc * dinv[r]);
    }
}

// K4: pull aggregation layer 1. 16 threads/node, 4 halves (8B) each.
__global__ __launch_bounds__(256) void k_pull1(
        const int* __restrict__ offs, const int* __restrict__ cnt,
        const int* __restrict__ ebuf, const float* __restrict__ dinv,
        const __half* __restrict__ hs1, __half* __restrict__ out1) {
    int idx = blockIdx.x * blockDim.x + threadIdx.x;
    int d = idx >> 4, sub = idx & 15;
    if (d >= N_NODES) return;
    const uint2* h4 = (const uint2*)hs1;      // 4 halves per uint2, 16 per row
    float4 acc = cvt4(h4[d * 16 + sub]);      // self-loop term
    int base = offs[d], c = cnt[d];
    if (c > 0) {
        int s = ebuf[base];
        int j = 0;
        for (; j + 1 < c; ++j) {
            int s2 = ebuf[base + j + 1];      // prefetch next id
            float4 v = cvt4(h4[s * 16 + sub]);
            acc.x += v.x; acc.y += v.y; acc.z += v.z; acc.w += v.w;
            s = s2;
        }
        float4 v = cvt4(h4[s * 16 + sub]);
        acc.x += v.x; acc.y += v.y; acc.z += v.z; acc.w += v.w;
    }
    float di = dinv[d];
    __half2 lo = __floats2half2_rn(acc.x * di, acc.y * di);
    __half2 hi = __floats2half2_rn(acc.z * di, acc.w * di);
    uint2 o; o.x = *(unsigned*)&lo; o.y = *(unsigned*)&hi;
    ((uint2*)out1)[d * 16 + sub] = o;
}

// K5: BN1 column stats over fp16 out1
__global__ __launch_bounds__(256) void k5_stats1(
        const __half* __restrict__ out1, float* __restrict__ stats) {
    int c = threadIdx.x & 63;
    int wv = threadIdx.x >> 6;
    float s = 0.f, q = 0.f;
    int stride = gridDim.x * 4;
    for (int r = blockIdx.x * 4 + wv; r < N_NODES; r += stride) {
        float x = __half2float(out1[r * 64 + c]);
        s += x;
        q = fmaf(x, x, q);
    }
    __shared__ float ls[4][64], lq[4][64];
    ls[wv][c] = s; lq[wv][c] = q;
    __syncthreads();
    if (threadIdx.x < 64) {
        s = ls[0][c] + ls[1][c] + ls[2][c] + ls[3][c];
        q = lq[0][c] + lq[1][c] + lq[2][c] + lq[3][c];
        unsafeAtomicAdd(&stats[c], s);
        unsafeAtomicAdd(&stats[64 + c], q);
    }
}

// K6: s1 = relu(bn1(out1)); hs2 = (s1 @ w2) * dinv[row]. BN1 finalize inline.
__global__ __launch_bounds__(256) void k7_xw2(
        const __half* __restrict__ out1, const float* __restrict__ stats,
        const float* __restrict__ g1, const float* __restrict__ beta1,
        const float* __restrict__ w2, const float* __restrict__ dinv,
        float* __restrict__ hs2) {
    __shared__ float lsc[64], lsh[64];
    int c = threadIdx.x & 63;
    int wv = threadIdx.x >> 6;
    if (threadIdx.x < 64) {
        float invn = 1.f / (float)N_NODES;
        float m = stats[c] * invn;
        float v = stats[64 + c] * invn - m * m;
        float inv = rsqrtf(v + BN_EPS);
        float sc = g1[c] * inv;
        lsc[c] = sc;
        lsh[c] = beta1[c] - m * sc;
    }
    __syncthreads();
    float s0 = lsc[c], h0 = lsh[c];
    float w20 = w2[c * 2], w21 = w2[c * 2 + 1];
    int stride = gridDim.x * 4;
    for (int r = blockIdx.x * 4 + wv; r < N_NODES; r += stride) {
        float x = __half2float(out1[r * 64 + c]);
        float y = fmaxf(fmaf(x, s0, h0), 0.f);
        float p0 = y * w20, p1 = y * w21;
#pragma unroll
        for (int m = 32; m; m >>= 1) {
            p0 += __shfl_xor(p0, m);
            p1 += __shfl_xor(p1, m);
        }
        if (c == 0) {
            float di = dinv[r];
            hs2[r * 2] = p0 * di;
            hs2[r * 2 + 1] = p1 * di;
        }
    }
}

// K7: pull aggregation layer 2 + fused BN2 stats
__global__ __launch_bounds__(256) void k_pull2(
        const int* __restrict__ offs, const int* __restrict__ cnt,
        const int* __restrict__ ebuf, const float* __restrict__ dinv,
        const float* __restrict__ hs2, float* __restrict__ out2,
        float* __restrict__ stats2) {
    int d = blockIdx.x * blockDim.x + threadIdx.x;
    float o0 = 0.f, o1 = 0.f;
    if (d < N_NODES) {
        const float2* h2 = (const float2*)hs2;
        float2 self = h2[d];
        o0 = self.x; o1 = self.y;
        int base = offs[d], c = cnt[d];
        for (int j = 0; j < c; ++j) {
            int s = ebuf[base + j];
            float2 v = h2[s];
            o0 += v.x; o1 += v.y;
        }
        float di = dinv[d];
        o0 *= di; o1 *= di;
        ((float2*)out2)[d] = make_float2(o0, o1);
    }
    // block-reduce sums & sumsq (threads past N contribute 0)
    float s0 = o0, s1 = o1, q0 = o0 * o0, q1 = o1 * o1;
#pragma unroll
    for (int m = 32; m; m >>= 1) {
        s0 += __shfl_down(s0, m); s1 += __shfl_down(s1, m);
        q0 += __shfl_down(q0, m); q1 += __shfl_down(q1, m);
    }
    __shared__ float red[4][4];
    int wv = threadIdx.x >> 6;
    if ((threadIdx.x & 63) == 0) {
        red[0][wv] = s0; red[1][wv] = s1; red[2][wv] = q0; red[3][wv] = q1;
    }
    __syncthreads();
    if (threadIdx.x < 4) {
        int i = threadIdx.x;
        float v = red[i][0] + red[i][1] + red[i][2] + red[i][3];
        unsafeAtomicAdd(&stats2[i], v);
    }
}

// K8: BN2 + sigmoid + softmax epilogue
__global__ __launch_bounds__(256) void k10_head(
        const float* __restrict__ out2, const float* __restrict__ stats2,
        const float* __restrict__ g2, const float* __restrict__ beta2,
        float* __restrict__ out) {
    int r = blockIdx.x * blockDim.x + threadIdx.x;
    if (r >= N_NODES) return;
    float invn = 1.f / (float)N_NODES;
    float m0 = stats2[0] * invn, m1 = stats2[1] * invn;
    float v0 = stats2[2] * invn - m0 * m0;
    float v1 = stats2[3] * invn - m1 * m1;
    float i0 = rsqrtf(v0 + BN_EPS), i1 = rsqrtf(v1 + BN_EPS);
    float sc0 = g2[0] * i0, sc1 = g2[1] * i1;
    float sh0 = beta2[0] - m0 * sc0, sh1 = beta2[1] - m1 * sc1;
    float2 x = ((const float2*)out2)[r];
    float y0 = fmaf(x.x, sc0, sh0), y1 = fmaf(x.y, sc1, sh1);
    out[r * 2] = 1.f / (1.f + __expf(-y0));
    out[r * 2 + 1] = 1.f / (1.f + __expf(-y1));
    out[2 * N_NODES + r * 2] = 1.f / (1.f + __expf(y1 - y0));
    out[2 * N_NODES + r * 2 + 1] = 1.f / (1.f + __expf(y0 - y1));
}

extern "C" void kernel_launch(void* const* d_in, const int* in_sizes, int n_in,
                              void* d_out, int out_size, void* d_ws, size_t ws_size,
                              hipStream_t stream) {
    const int*   edge  = (const int*)d_in[0];          // (2,E): [0,E)=src, [E,2E)=dst
    const float* u_S   = (const float*)d_in[1];
    const float* w1    = (const float*)d_in[2];
    const float* g1    = (const float*)d_in[4];
    const float* beta1 = (const float*)d_in[5];
    const float* w2    = (const float*)d_in[6];
    const float* g2    = (const float*)d_in[8];
    const float* beta2 = (const float*)d_in[9];
    float* out = (float*)d_out;

    float*  ws     = (float*)d_ws;
    int*    gcur   = (int*)(ws + OFF_GCUR);
    int*    cnt    = (int*)(ws + OFF_CNT);
    float*  dinv   = ws + OFF_DINV;
    int*    offs   = (int*)(ws + OFF_OFFS);
    int*    ebuf   = (int*)(ws + OFF_EBUF);
    float*  stats1 = ws + OFF_STATS1;
    float*  stats2 = ws + OFF_STATS2;
    __half* hs1    = (__half*)(ws + OFF_HS1);
    int*    binned = (int*)(ws + OFF_BINNED);   // alias of hs1 head; dead before k3_xw1
    __half* out1   = (__half*)(ws + OFF_OUT1);
    float*  hs2    = ws + OFF_HS2;
    float*  out2   = ws + OFF_OUT2;

    const int* src = edge;
    const int* dst = edge + N_EDGES;

    k0_init<<<1, 256, 0, stream>>>(gcur, stats1);
    k_bin<<<NBLK_BIN, 256, 0, stream>>>(src, dst, gcur, binned);
    k_csr<<<NBUCK, 256, 0, stream>>>(gcur, binned, cnt, dinv, offs, ebuf);
    k3_xw1<<<2048, 256, 0, stream>>>(u_S, w1, dinv, hs1);
    k_pull1<<<(N_NODES * 16 + 255) / 256, 256, 0, stream>>>(offs, cnt, ebuf, dinv, hs1, out1);
    k5_stats1<<<256, 256, 0, stream>>>(out1, stats1);
    k7_xw2<<<2048, 256, 0, stream>>>(out1, stats1, g1, beta1, w2, dinv, hs2);
    k_pull2<<<(N_NODES + 255) / 256, 256, 0, stream>>>(offs, cnt, ebuf, dinv, hs2, out2, stats2);
    k10_head<<<(N_NODES + 255) / 256, 256, 0, stream>>>(out2, stats2, g2, beta2, out);
}

// Round 6
// 247.037 us; speedup vs baseline: 7.1704x; 1.1045x over previous
//
#include <hip/hip_runtime.h>
#include <hip/hip_fp16.h>

#define N_NODES 100000
#define N_EDGES 1600000
#define BN_EPS 1e-5f

#define NBUCK 256          // dst buckets
#define NPB   391          // nodes per bucket (ceil(100000/256)); last has 295
#define BCAP  8192         // edge capacity per bucket (mean 6250, ~24 sigma margin)
#define EPB_BIN 4096       // edges per k_bin block
#define NBLK_BIN ((N_EDGES + EPB_BIN - 1) / EPB_BIN)   // 391

#define K3_NBLK 1024       // k3_xw1 grid

// ---- workspace layout (32-bit units) ----
#define OFF_GCUR   0            // 256 ints: bucket fill cursors (into binned)
#define OFF_CNT    256          // N ints
#define OFF_DINV   100352       // N floats
#define OFF_OFFS   200448       // N ints (gapped CSR offsets into ebuf)
#define OFF_EBUF   300544       // NBUCK*BCAP = 2,097,152 ints (gapped)
#define OFF_STATS1 2397696      // 128 floats: sum[64], sumsq[64]
#define OFF_STATS2 2397824      // 4 floats: s0,s1,q0,q1
#define OFF_HS1    2398016      // half[N*64] = 3.2M units (head aliases binned pre-k3)
#define OFF_BINNED OFF_HS1      // int[NBUCK*BCAP] = 2,097,152 < 3,200,000
#define OFF_OUT1   5598016      // half[N*64] = 3.2M units
#define OFF_HS2    8798016      // N*2 floats
#define OFF_OUT2   8998016      // N*2 floats
// total 9,198,016 * 4B = 36.8 MB

__device__ inline float4 cvt4(uint2 v) {
    __half2 a = *(__half2*)&v.x, b = *(__half2*)&v.y;
    float2 fa = __half22float2(a), fb = __half22float2(b);
    return make_float4(fa.x, fa.y, fb.x, fb.y);
}

// K0: init bucket cursors to slice bases; zero stat accumulators
__global__ __launch_bounds__(256) void k0_init(int* __restrict__ gcur,
                                               float* __restrict__ stats) {
    int t = threadIdx.x;
    gcur[t] = t * BCAP;
    if (t < 132) stats[t] = 0.f;   // stats1(128)+stats2(4) contiguous
}

// K1: radix partition edges into 256 dst-buckets; store packed (src | ldst<<17)
__global__ __launch_bounds__(256) void k_bin(
        const int* __restrict__ src, const int* __restrict__ dst,
        int* __restrict__ gcur, int* __restrict__ binned) {
    __shared__ int hist[NBUCK];
    __shared__ int lcur[NBUCK];
    int t = threadIdx.x, b = blockIdx.x;
    hist[t] = 0;
    __syncthreads();
    int e0 = b * EPB_BIN;
    int pkreg[16], bkreg[16];
#pragma unroll
    for (int i = 0; i < 16; ++i) {
        int e = e0 + t + i * 256;              // coalesced
        if (e < N_EDGES) {
            int s = src[e], d = dst[e];
            int bk = d / NPB;
            bkreg[i] = bk;
            pkreg[i] = s | ((d - bk * NPB) << 17);
            atomicAdd(&hist[bk], 1);
        } else bkreg[i] = -1;
    }
    __syncthreads();
    int h = hist[t];
    lcur[t] = (h > 0) ? atomicAdd(&gcur[t], h) : 0;   // reserve contiguous run
    __syncthreads();
#pragma unroll
    for (int i = 0; i < 16; ++i) {
        if (bkreg[i] >= 0) {
            int bk = bkreg[i];
            int pos = atomicAdd(&lcur[bk], 1);
            if (pos < (bk + 1) * BCAP)          // overflow guard (never taken)
                binned[pos] = pkreg[i];
        }
    }
}

// K2: per-bucket CSR build (LDS-only histogram/scan/cursors) + cnt/offs/dinv
__global__ __launch_bounds__(256) void k_csr(
        const int* __restrict__ gcur, const int* __restrict__ binned,
        int* __restrict__ cnt, float* __restrict__ dinv,
        int* __restrict__ offs, int* __restrict__ ebuf) {
    int b = blockIdx.x, t = threadIdx.x;
    int nb0 = b * NPB;
    int nn = min(NPB, N_NODES - nb0);          // 391 (or 295 for last)
    __shared__ int lcnt[NPB];
    __shared__ int lcur[NPB];
    __shared__ int sc[512];
    for (int i = t; i < NPB; i += 256) lcnt[i] = 0;
    __syncthreads();
    int base = b * BCAP;
    int m = min(gcur[b] - base, BCAP);
    for (int j = t; j < m; j += 256)
        atomicAdd(&lcnt[((unsigned)binned[base + j]) >> 17], 1);
    __syncthreads();
    // exclusive scan of lcnt[0..NPB) via Hillis-Steele over 512 slots
    sc[t] = (t < NPB) ? lcnt[t] : 0;
    sc[256 + t] = (256 + t < NPB) ? lcnt[256 + t] : 0;
    __syncthreads();
    for (int off = 1; off < 512; off <<= 1) {
        int v0 = (t >= off) ? sc[t - off] : 0;
        int i1 = t + 256;
        int v1 = (i1 >= off) ? sc[i1 - off] : 0;
        __syncthreads();
        sc[t] += v0; sc[i1] += v1;
        __syncthreads();
    }
    for (int i = t; i < nn; i += 256) {
        int c = lcnt[i];
        int excl = sc[i] - c;
        lcur[i] = excl;
        offs[nb0 + i] = base + excl;           // gapped global CSR offset
        cnt[nb0 + i] = c;
        dinv[nb0 + i] = rsqrtf((float)(1 + c));
    }
    __syncthreads();
    for (int j = t; j < m; j += 256) {
        unsigned v = (unsigned)binned[base + j];
        int pos = atomicAdd(&lcur[v >> 17], 1);
        ebuf[base + pos] = (int)(v & 0x1FFFFu); // confined to 32KB slice
    }
}

// K3: hs1 = fp16( (u_S @ w1) * dinv[row] )
// Lane owns column c=lane; w[:,c] held in 64 VGPRs; u rows via wave-uniform
// scalar loads (SGPR broadcast); 4 rows/iter -> 4 independent FMA chains.
// No LDS, no barriers.
__global__ __launch_bounds__(256) void k3_xw1(
        const float* __restrict__ u, const float* __restrict__ w1g,
        const float* __restrict__ dinv, __half* __restrict__ hs1) {
    int lane = threadIdx.x & 63;
    float wreg[64];
#pragma unroll
    for (int k = 0; k < 64; ++k) wreg[k] = w1g[k * 64 + lane];   // coalesced
    int wg = __builtin_amdgcn_readfirstlane(blockIdx.x * 4 + (threadIdx.x >> 6));
    const int NW = K3_NBLK * 4;
    for (int g = wg; g < N_NODES / 4; g += NW) {      // 25000 row-groups
        const float* p = u + (size_t)g * 256;         // uniform base -> s_load
        float a0 = 0.f, a1 = 0.f, a2 = 0.f, a3 = 0.f;
#pragma unroll
        for (int k = 0; k < 64; ++k) {
            float w = wreg[k];
            a0 = fmaf(p[k],       w, a0);
            a1 = fmaf(p[64 + k],  w, a1);
            a2 = fmaf(p[128 + k], w, a2);
            a3 = fmaf(p[192 + k], w, a3);
        }
        int r = g * 4;
        float d0 = dinv[r], d1 = dinv[r + 1], d2 = dinv[r + 2], d3 = dinv[r + 3];
        hs1[(size_t)r * 64 + lane]           = __float2half(a0 * d0);
        hs1[(size_t)(r + 1) * 64 + lane]     = __float2half(a1 * d1);
        hs1[(size_t)(r + 2) * 64 + lane]     = __float2half(a2 * d2);
        hs1[(size_t)(r + 3) * 64 + lane]     = __float2half(a3 * d3);
    }
}

// K4: pull aggregation layer 1. 16 threads/node, 4 halves (8B) each.
__global__ __launch_bounds__(256) void k_pull1(
        const int* __restrict__ offs, const int* __restrict__ cnt,
        const int* __restrict__ ebuf, const float* __restrict__ dinv,
        const __half* __restrict__ hs1, __half* __restrict__ out1) {
    int idx = blockIdx.x * blockDim.x + threadIdx.x;
    int d = idx >> 4, sub = idx & 15;
    if (d >= N_NODES) return;
    const uint2* h4 = (const uint2*)hs1;      // 4 halves per uint2, 16 per row
    float4 acc = cvt4(h4[d * 16 + sub]);      // self-loop term
    int base = offs[d], c = cnt[d];
    if (c > 0) {
        int s = ebuf[base];
        int j = 0;
        for (; j + 1 < c; ++j) {
            int s2 = ebuf[base + j + 1];      // prefetch next id
            float4 v = cvt4(h4[s * 16 + sub]);
            acc.x += v.x; acc.y += v.y; acc.z += v.z; acc.w += v.w;
            s = s2;
        }
        float4 v = cvt4(h4[s * 16 + sub]);
        acc.x += v.x; acc.y += v.y; acc.z += v.z; acc.w += v.w;
    }
    float di = dinv[d];
    __half2 lo = __floats2half2_rn(acc.x * di, acc.y * di);
    __half2 hi = __floats2half2_rn(acc.z * di, acc.w * di);
    uint2 o; o.x = *(unsigned*)&lo; o.y = *(unsigned*)&hi;
    ((uint2*)out1)[d * 16 + sub] = o;
}

// K5: BN1 column stats over fp16 out1 — uint4 (8 halves/lane), shfl reduce.
__global__ __launch_bounds__(256) void k5_stats1(
        const __half* __restrict__ out1, float* __restrict__ stats) {
    int tid = blockIdx.x * blockDim.x + threadIdx.x;
    int gsz = gridDim.x * blockDim.x;           // multiple of 8
    const uint4* p = (const uint4*)out1;
    const int total = N_NODES * 8;              // N*64/8 vectors
    float s[8], q[8];
#pragma unroll
    for (int j = 0; j < 8; ++j) { s[j] = 0.f; q[j] = 0.f; }
    for (int i = tid; i < total; i += gsz) {    // (i&7) == (tid&7) invariant
        uint4 v = p[i];
        unsigned w[4] = {v.x, v.y, v.z, v.w};
#pragma unroll
        for (int h = 0; h < 4; ++h) {
            float2 f = __half22float2(*(__half2*)&w[h]);
            s[2*h]   += f.x; q[2*h]   = fmaf(f.x, f.x, q[2*h]);
            s[2*h+1] += f.y; q[2*h+1] = fmaf(f.y, f.y, q[2*h+1]);
        }
    }
    // lanes sharing (lane&7) hold the same col-group: reduce over bits 3..5
#pragma unroll
    for (int m = 8; m < 64; m <<= 1) {
#pragma unroll
        for (int j = 0; j < 8; ++j) {
            s[j] += __shfl_xor(s[j], m);
            q[j] += __shfl_xor(q[j], m);
        }
    }
    __shared__ float red[4][128];
    int lane = threadIdx.x & 63, wv = threadIdx.x >> 6;
    if (lane < 8) {
        int c0 = lane * 8;
#pragma unroll
        for (int j = 0; j < 8; ++j) {
            red[wv][c0 + j] = s[j];
            red[wv][64 + c0 + j] = q[j];
        }
    }
    __syncthreads();
    if (threadIdx.x < 128) {
        int t = threadIdx.x;
        float v = red[0][t] + red[1][t] + red[2][t] + red[3][t];
        unsafeAtomicAdd(&stats[t], v);          // stats[c]=sum, stats[64+c]=sumsq
    }
}

// K6: s1 = relu(bn1(out1)); hs2 = (s1 @ w2) * dinv[row]. BN1 finalize inline.
__global__ __launch_bounds__(256) void k7_xw2(
        const __half* __restrict__ out1, const float* __restrict__ stats,
        const float* __restrict__ g1, const float* __restrict__ beta1,
        const float* __restrict__ w2, const float* __restrict__ dinv,
        float* __restrict__ hs2) {
    __shared__ float lsc[64], lsh[64];
    int c = threadIdx.x & 63;
    int wv = threadIdx.x >> 6;
    if (threadIdx.x < 64) {
        float invn = 1.f / (float)N_NODES;
        float m = stats[c] * invn;
        float v = stats[64 + c] * invn - m * m;
        float inv = rsqrtf(v + BN_EPS);
        float sc = g1[c] * inv;
        lsc[c] = sc;
        lsh[c] = beta1[c] - m * sc;
    }
    __syncthreads();
    float s0 = lsc[c], h0 = lsh[c];
    float w20 = w2[c * 2], w21 = w2[c * 2 + 1];
    int stride = gridDim.x * 4;
    for (int r = blockIdx.x * 4 + wv; r < N_NODES; r += stride) {
        float x = __half2float(out1[r * 64 + c]);
        float y = fmaxf(fmaf(x, s0, h0), 0.f);
        float p0 = y * w20, p1 = y * w21;
#pragma unroll
        for (int m = 32; m; m >>= 1) {
            p0 += __shfl_xor(p0, m);
            p1 += __shfl_xor(p1, m);
        }
        if (c == 0) {
            float di = dinv[r];
            hs2[r * 2] = p0 * di;
            hs2[r * 2 + 1] = p1 * di;
        }
    }
}

// K7: pull aggregation layer 2 + fused BN2 stats
__global__ __launch_bounds__(256) void k_pull2(
        const int* __restrict__ offs, const int* __restrict__ cnt,
        const int* __restrict__ ebuf, const float* __restrict__ dinv,
        const float* __restrict__ hs2, float* __restrict__ out2,
        float* __restrict__ stats2) {
    int d = blockIdx.x * blockDim.x + threadIdx.x;
    float o0 = 0.f, o1 = 0.f;
    if (d < N_NODES) {
        const float2* h2 = (const float2*)hs2;
        float2 self = h2[d];
        o0 = self.x; o1 = self.y;
        int base = offs[d], c = cnt[d];
        for (int j = 0; j < c; ++j) {
            int s = ebuf[base + j];
            float2 v = h2[s];
            o0 += v.x; o1 += v.y;
        }
        float di = dinv[d];
        o0 *= di; o1 *= di;
        ((float2*)out2)[d] = make_float2(o0, o1);
    }
    // block-reduce sums & sumsq (threads past N contribute 0)
    float s0 = o0, s1 = o1, q0 = o0 * o0, q1 = o1 * o1;
#pragma unroll
    for (int m = 32; m; m >>= 1) {
        s0 += __shfl_down(s0, m); s1 += __shfl_down(s1, m);
        q0 += __shfl_down(q0, m); q1 += __shfl_down(q1, m);
    }
    __shared__ float red[4][4];
    int wv = threadIdx.x >> 6;
    if ((threadIdx.x & 63) == 0) {
        red[0][wv] = s0; red[1][wv] = s1; red[2][wv] = q0; red[3][wv] = q1;
    }
    __syncthreads();
    if (threadIdx.x < 4) {
        int i = threadIdx.x;
        float v = red[i][0] + red[i][1] + red[i][2] + red[i][3];
        unsafeAtomicAdd(&stats2[i], v);
    }
}

// K8: BN2 + sigmoid + softmax epilogue
__global__ __launch_bounds__(256) void k10_head(
        const float* __restrict__ out2, const float* __restrict__ stats2,
        const float* __restrict__ g2, const float* __restrict__ beta2,
        float* __restrict__ out) {
    int r = blockIdx.x * blockDim.x + threadIdx.x;
    if (r >= N_NODES) return;
    float invn = 1.f / (float)N_NODES;
    float m0 = stats2[0] * invn, m1 = stats2[1] * invn;
    float v0 = stats2[2] * invn - m0 * m0;
    float v1 = stats2[3] * invn - m1 * m1;
    float i0 = rsqrtf(v0 + BN_EPS), i1 = rsqrtf(v1 + BN_EPS);
    float sc0 = g2[0] * i0, sc1 = g2[1] * i1;
    float sh0 = beta2[0] - m0 * sc0, sh1 = beta2[1] - m1 * sc1;
    float2 x = ((const float2*)out2)[r];
    float y0 = fmaf(x.x, sc0, sh0), y1 = fmaf(x.y, sc1, sh1);
    out[r * 2] = 1.f / (1.f + __expf(-y0));
    out[r * 2 + 1] = 1.f / (1.f + __expf(-y1));
    out[2 * N_NODES + r * 2] = 1.f / (1.f + __expf(y1 - y0));
    out[2 * N_NODES + r * 2 + 1] = 1.f / (1.f + __expf(y0 - y1));
}

extern "C" void kernel_launch(void* const* d_in, const int* in_sizes, int n_in,
                              void* d_out, int out_size, void* d_ws, size_t ws_size,
                              hipStream_t stream) {
    const int*   edge  = (const int*)d_in[0];          // (2,E): [0,E)=src, [E,2E)=dst
    const float* u_S   = (const float*)d_in[1];
    const float* w1    = (const float*)d_in[2];
    const float* g1    = (const float*)d_in[4];
    const float* beta1 = (const float*)d_in[5];
    const float* w2    = (const float*)d_in[6];
    const float* g2    = (const float*)d_in[8];
    const float* beta2 = (const float*)d_in[9];
    float* out = (float*)d_out;

    float*  ws     = (float*)d_ws;
    int*    gcur   = (int*)(ws + OFF_GCUR);
    int*    cnt    = (int*)(ws + OFF_CNT);
    float*  dinv   = ws + OFF_DINV;
    int*    offs   = (int*)(ws + OFF_OFFS);
    int*    ebuf   = (int*)(ws + OFF_EBUF);
    float*  stats1 = ws + OFF_STATS1;
    float*  stats2 = ws + OFF_STATS2;
    __half* hs1    = (__half*)(ws + OFF_HS1);
    int*    binned = (int*)(ws + OFF_BINNED);   // alias of hs1 head; dead before k3_xw1
    __half* out1   = (__half*)(ws + OFF_OUT1);
    float*  hs2    = ws + OFF_HS2;
    float*  out2   = ws + OFF_OUT2;

    const int* src = edge;
    const int* dst = edge + N_EDGES;

    k0_init<<<1, 256, 0, stream>>>(gcur, stats1);
    k_bin<<<NBLK_BIN, 256, 0, stream>>>(src, dst, gcur, binned);
    k_csr<<<NBUCK, 256, 0, stream>>>(gcur, binned, cnt, dinv, offs, ebuf);
    k3_xw1<<<K3_NBLK, 256, 0, stream>>>(u_S, w1, dinv, hs1);
    k_pull1<<<(N_NODES * 16 + 255) / 256, 256, 0, stream>>>(offs, cnt, ebuf, dinv, hs1, out1);
    k5_stats1<<<256, 256, 0, stream>>>(out1, stats1);
    k7_xw2<<<2048, 256, 0, stream>>>(out1, stats1, g1, beta1, w2, dinv, hs2);
    k_pull2<<<(N_NODES + 255) / 256, 256, 0, stream>>>(offs, cnt, ebuf, dinv, hs2, out2, stats2);
    k10_head<<<(N_NODES + 255) / 256, 256, 0, stream>>>(out2, stats2, g2, beta2, out);
}

// Round 8
// 227.675 us; speedup vs baseline: 7.7802x; 1.0850x over previous
//
#include <hip/hip_runtime.h>
#include <hip/hip_fp16.h>

#define N_NODES 100000
#define N_EDGES 1600000
#define BN_EPS 1e-5f

#define NBUCK 256          // dst buckets
#define NPB   391          // nodes per bucket (ceil(100000/256)); last has 295
#define BCAP  8192         // edge capacity per bucket (mean 6250, ~24 sigma margin)
#define EPB_BIN 4096       // edges per k_bin block
#define NBLK_BIN ((N_EDGES + EPB_BIN - 1) / EPB_BIN)   // 391

// ---- workspace layout (32-bit units) ----
#define OFF_GCUR   0            // 256 ints: bucket fill cursors (into binned)
#define OFF_CNT    256          // N ints
#define OFF_DINV   100352       // N floats
#define OFF_OFFS   200448       // N ints (gapped CSR offsets into ebuf)
#define OFF_EBUF   300544       // NBUCK*BCAP = 2,097,152 ints (gapped)
#define OFF_STATS1 2397696      // 128 floats: sum[64], sumsq[64]
#define OFF_STATS2 2397824      // 4 floats: s0,s1,q0,q1
#define OFF_HS1    2398016      // half[N*64] = 3.2M units (head aliases binned pre-k3)
#define OFF_BINNED OFF_HS1      // int[NBUCK*BCAP] = 2,097,152 < 3,200,000
#define OFF_OUT1   5598016      // half[N*64] = 3.2M units
#define OFF_HS2    8798016      // N*2 floats
#define OFF_OUT2   8998016      // N*2 floats
// total 9,198,016 * 4B = 36.8 MB

typedef _Float16 f16x8 __attribute__((ext_vector_type(8)));
typedef float    f32x4 __attribute__((ext_vector_type(4)));

__device__ inline float4 cvt4(uint2 v) {
    __half2 a = *(__half2*)&v.x, b = *(__half2*)&v.y;
    float2 fa = __half22float2(a), fb = __half22float2(b);
    return make_float4(fa.x, fa.y, fb.x, fb.y);
}

// K0: init bucket cursors to slice bases; zero stat accumulators
__global__ __launch_bounds__(256) void k0_init(int* __restrict__ gcur,
                                               float* __restrict__ stats) {
    int t = threadIdx.x;
    gcur[t] = t * BCAP;
    if (t < 132) stats[t] = 0.f;   // stats1(128)+stats2(4) contiguous
}

// K1: radix partition edges into 256 dst-buckets; store packed (src | ldst<<17)
__global__ __launch_bounds__(256) void k_bin(
        const int* __restrict__ src, const int* __restrict__ dst,
        int* __restrict__ gcur, int* __restrict__ binned) {
    __shared__ int hist[NBUCK];
    __shared__ int lcur[NBUCK];
    int t = threadIdx.x, b = blockIdx.x;
    hist[t] = 0;
    __syncthreads();
    int e0 = b * EPB_BIN;
    int pkreg[16], bkreg[16];
#pragma unroll
    for (int i = 0; i < 16; ++i) {
        int e = e0 + t + i * 256;              // coalesced
        if (e < N_EDGES) {
            int s = src[e], d = dst[e];
            int bk = d / NPB;
            bkreg[i] = bk;
            pkreg[i] = s | ((d - bk * NPB) << 17);
            atomicAdd(&hist[bk], 1);
        } else bkreg[i] = -1;
    }
    __syncthreads();
    int h = hist[t];
    lcur[t] = (h > 0) ? atomicAdd(&gcur[t], h) : 0;   // reserve contiguous run
    __syncthreads();
#pragma unroll
    for (int i = 0; i < 16; ++i) {
        if (bkreg[i] >= 0) {
            int bk = bkreg[i];
            int pos = atomicAdd(&lcur[bk], 1);
            if (pos < (bk + 1) * BCAP)          // overflow guard (never taken)
                binned[pos] = pkreg[i];
        }
    }
}

// K2: per-bucket CSR build (LDS-only histogram/scan/cursors) + cnt/offs/dinv
__global__ __launch_bounds__(256) void k_csr(
        const int* __restrict__ gcur, const int* __restrict__ binned,
        int* __restrict__ cnt, float* __restrict__ dinv,
        int* __restrict__ offs, int* __restrict__ ebuf) {
    int b = blockIdx.x, t = threadIdx.x;
    int nb0 = b * NPB;
    int nn = min(NPB, N_NODES - nb0);          // 391 (or 295 for last)
    __shared__ int lcnt[NPB];
    __shared__ int lcur[NPB];
    __shared__ int sc[512];
    for (int i = t; i < NPB; i += 256) lcnt[i] = 0;
    __syncthreads();
    int base = b * BCAP;
    int m = min(gcur[b] - base, BCAP);
    for (int j = t; j < m; j += 256)
        atomicAdd(&lcnt[((unsigned)binned[base + j]) >> 17], 1);
    __syncthreads();
    // exclusive scan of lcnt[0..NPB) via Hillis-Steele over 512 slots
    sc[t] = (t < NPB) ? lcnt[t] : 0;
    sc[256 + t] = (256 + t < NPB) ? lcnt[256 + t] : 0;
    __syncthreads();
    for (int off = 1; off < 512; off <<= 1) {
        int v0 = (t >= off) ? sc[t - off] : 0;
        int i1 = t + 256;
        int v1 = (i1 >= off) ? sc[i1 - off] : 0;
        __syncthreads();
        sc[t] += v0; sc[i1] += v1;
        __syncthreads();
    }
    for (int i = t; i < nn; i += 256) {
        int c = lcnt[i];
        int excl = sc[i] - c;
        lcur[i] = excl;
        offs[nb0 + i] = base + excl;           // gapped global CSR offset
        cnt[nb0 + i] = c;
        dinv[nb0 + i] = rsqrtf((float)(1 + c));
    }
    __syncthreads();
    for (int j = t; j < m; j += 256) {
        unsigned v = (unsigned)binned[base + j];
        int pos = atomicAdd(&lcur[v >> 17], 1);
        ebuf[base + pos] = (int)(v & 0x1FFFFu); // confined to 32KB slice
    }
}

// K3: hs1 = fp16( (u_S @ w1) * dinv[row] ) via MFMA.
// One wave per 16-row group: 8 loop-invariant B frags (w1 in VGPRs),
// 2 A frags from u (fp32->fp16), 8 x mfma_f32_16x16x32_f16, no LDS/barriers.
// Layouts (gfx950): A/B: row|col=lane&15, k=(lane>>4)*8+i ; D: col=lane&15,
// row=(lane>>4)*4+reg.
__global__ __launch_bounds__(256) void k3_xw1(
        const float* __restrict__ u, const float* __restrict__ w1g,
        const float* __restrict__ dinv, __half* __restrict__ hs1) {
    int t = threadIdx.x;
    int lane = t & 63, wid = t >> 6;
    int g = blockIdx.x * 4 + wid;              // 16-row group id
    if (g >= N_NODES / 16) return;             // wave-uniform exit
    int r = lane & 15, kb = lane >> 4;

    f16x8 bf[4][2];                            // [col-tile][k-half]
#pragma unroll
    for (int ct = 0; ct < 4; ++ct) {
#pragma unroll
        for (int kh = 0; kh < 2; ++kh) {
            int c = ct * 16 + r;
            int k0 = kh * 32 + kb * 8;
            f16x8 b;
#pragma unroll
            for (int i = 0; i < 8; ++i) b[i] = (_Float16)w1g[(k0 + i) * 64 + c];
            bf[ct][kh] = b;
        }
    }

    const float* up = u + (size_t)g * 16 * 64;
    f16x8 af[2];
#pragma unroll
    for (int kh = 0; kh < 2; ++kh) {
        const float* p = up + r * 64 + kh * 32 + kb * 8;
        float4 v0 = *(const float4*)p;
        float4 v1 = *(const float4*)(p + 4);
        f16x8 a;
        a[0] = (_Float16)v0.x; a[1] = (_Float16)v0.y;
        a[2] = (_Float16)v0.z; a[3] = (_Float16)v0.w;
        a[4] = (_Float16)v1.x; a[5] = (_Float16)v1.y;
        a[6] = (_Float16)v1.z; a[7] = (_Float16)v1.w;
        af[kh] = a;
    }

    f32x4 acc[4];
#pragma unroll
    for (int ct = 0; ct < 4; ++ct) { acc[ct][0]=0.f; acc[ct][1]=0.f; acc[ct][2]=0.f; acc[ct][3]=0.f; }
#pragma unroll
    for (int ct = 0; ct < 4; ++ct) {
        acc[ct] = __builtin_amdgcn_mfma_f32_16x16x32_f16(af[0], bf[ct][0], acc[ct], 0, 0, 0);
        acc[ct] = __builtin_amdgcn_mfma_f32_16x16x32_f16(af[1], bf[ct][1], acc[ct], 0, 0, 0);
    }

    int r0 = g * 16;
    float4 dv = *(const float4*)&dinv[r0 + kb * 4];
    float dvv[4] = {dv.x, dv.y, dv.z, dv.w};
#pragma unroll
    for (int ct = 0; ct < 4; ++ct) {
#pragma unroll
        for (int reg = 0; reg < 4; ++reg) {
            int row = r0 + kb * 4 + reg;
            int col = ct * 16 + r;
            hs1[(size_t)row * 64 + col] = __float2half(acc[ct][reg] * dvv[reg]);
        }
    }
}

// K4: pull aggregation layer 1. 16 threads/node, 4 halves (8B) each.
__global__ __launch_bounds__(256) void k_pull1(
        const int* __restrict__ offs, const int* __restrict__ cnt,
        const int* __restrict__ ebuf, const float* __restrict__ dinv,
        const __half* __restrict__ hs1, __half* __restrict__ out1) {
    int idx = blockIdx.x * blockDim.x + threadIdx.x;
    int d = idx >> 4, sub = idx & 15;
    if (d >= N_NODES) return;
    const uint2* h4 = (const uint2*)hs1;      // 4 halves per uint2, 16 per row
    float4 acc = cvt4(h4[d * 16 + sub]);      // self-loop term
    int base = offs[d], c = cnt[d];
    if (c > 0) {
        int s = ebuf[base];
        int j = 0;
        for (; j + 1 < c; ++j) {
            int s2 = ebuf[base + j + 1];      // prefetch next id
            float4 v = cvt4(h4[s * 16 + sub]);
            acc.x += v.x; acc.y += v.y; acc.z += v.z; acc.w += v.w;
            s = s2;
        }
        float4 v = cvt4(h4[s * 16 + sub]);
        acc.x += v.x; acc.y += v.y; acc.z += v.z; acc.w += v.w;
    }
    float di = dinv[d];
    __half2 lo = __floats2half2_rn(acc.x * di, acc.y * di);
    __half2 hi = __floats2half2_rn(acc.z * di, acc.w * di);
    uint2 o; o.x = *(unsigned*)&lo; o.y = *(unsigned*)&hi;
    ((uint2*)out1)[d * 16 + sub] = o;
}

// K5: BN1 column stats over fp16 out1 — uint4 (8 halves/lane), shfl reduce.
__global__ __launch_bounds__(256) void k5_stats1(
        const __half* __restrict__ out1, float* __restrict__ stats) {
    int tid = blockIdx.x * blockDim.x + threadIdx.x;
    int gsz = gridDim.x * blockDim.x;           // multiple of 8
    const uint4* p = (const uint4*)out1;
    const int total = N_NODES * 8;              // N*64/8 vectors
    float s[8], q[8];
#pragma unroll
    for (int j = 0; j < 8; ++j) { s[j] = 0.f; q[j] = 0.f; }
    for (int i = tid; i < total; i += gsz) {    // (i&7) == (tid&7) invariant
        uint4 v = p[i];
        unsigned w[4] = {v.x, v.y, v.z, v.w};
#pragma unroll
        for (int h = 0; h < 4; ++h) {
            float2 f = __half22float2(*(__half2*)&w[h]);
            s[2*h]   += f.x; q[2*h]   = fmaf(f.x, f.x, q[2*h]);
            s[2*h+1] += f.y; q[2*h+1] = fmaf(f.y, f.y, q[2*h+1]);
        }
    }
    // lanes sharing (lane&7) hold the same col-group: reduce over bits 3..5
#pragma unroll
    for (int m = 8; m < 64; m <<= 1) {
#pragma unroll
        for (int j = 0; j < 8; ++j) {
            s[j] += __shfl_xor(s[j], m);
            q[j] += __shfl_xor(q[j], m);
        }
    }
    __shared__ float red[4][128];
    int lane = threadIdx.x & 63, wv = threadIdx.x >> 6;
    if (lane < 8) {
        int c0 = lane * 8;
#pragma unroll
        for (int j = 0; j < 8; ++j) {
            red[wv][c0 + j] = s[j];
            red[wv][64 + c0 + j] = q[j];
        }
    }
    __syncthreads();
    if (threadIdx.x < 128) {
        int t = threadIdx.x;
        float v = red[0][t] + red[1][t] + red[2][t] + red[3][t];
        unsafeAtomicAdd(&stats[t], v);          // stats[c]=sum, stats[64+c]=sumsq
    }
}

// K6: s1 = relu(bn1(out1)); hs2 = (s1 @ w2) * dinv[row]. BN1 finalize inline.
__global__ __launch_bounds__(256) void k7_xw2(
        const __half* __restrict__ out1, const float* __restrict__ stats,
        const float* __restrict__ g1, const float* __restrict__ beta1,
        const float* __restrict__ w2, const float* __restrict__ dinv,
        float* __restrict__ hs2) {
    __shared__ float lsc[64], lsh[64];
    int c = threadIdx.x & 63;
    int wv = threadIdx.x >> 6;
    if (threadIdx.x < 64) {
        float invn = 1.f / (float)N_NODES;
        float m = stats[c] * invn;
        float v = stats[64 + c] * invn - m * m;
        float inv = rsqrtf(v + BN_EPS);
        float sc = g1[c] * inv;
        lsc[c] = sc;
        lsh[c] = beta1[c] - m * sc;
    }
    __syncthreads();
    float s0 = lsc[c], h0 = lsh[c];
    float w20 = w2[c * 2], w21 = w2[c * 2 + 1];
    int stride = gridDim.x * 4;
    for (int r = blockIdx.x * 4 + wv; r < N_NODES; r += stride) {
        float x = __half2float(out1[r * 64 + c]);
        float y = fmaxf(fmaf(x, s0, h0), 0.f);
        float p0 = y * w20, p1 = y * w21;
#pragma unroll
        for (int m = 32; m; m >>= 1) {
            p0 += __shfl_xor(p0, m);
            p1 += __shfl_xor(p1, m);
        }
        if (c == 0) {
            float di = dinv[r];
            hs2[r * 2] = p0 * di;
            hs2[r * 2 + 1] = p1 * di;
        }
    }
}

// K7: pull aggregation layer 2 + fused BN2 stats
__global__ __launch_bounds__(256) void k_pull2(
        const int* __restrict__ offs, const int* __restrict__ cnt,
        const int* __restrict__ ebuf, const float* __restrict__ dinv,
        const float* __restrict__ hs2, float* __restrict__ out2,
        float* __restrict__ stats2) {
    int d = blockIdx.x * blockDim.x + threadIdx.x;
    float o0 = 0.f, o1 = 0.f;
    if (d < N_NODES) {
        const float2* h2 = (const float2*)hs2;
        float2 self = h2[d];
        o0 = self.x; o1 = self.y;
        int base = offs[d], c = cnt[d];
        for (int j = 0; j < c; ++j) {
            int s = ebuf[base + j];
            float2 v = h2[s];
            o0 += v.x; o1 += v.y;
        }
        float di = dinv[d];
        o0 *= di; o1 *= di;
        ((float2*)out2)[d] = make_float2(o0, o1);
    }
    // block-reduce sums & sumsq (threads past N contribute 0)
    float s0 = o0, s1 = o1, q0 = o0 * o0, q1 = o1 * o1;
#pragma unroll
    for (int m = 32; m; m >>= 1) {
        s0 += __shfl_down(s0, m); s1 += __shfl_down(s1, m);
        q0 += __shfl_down(q0, m); q1 += __shfl_down(q1, m);
    }
    __shared__ float red[4][4];
    int wv = threadIdx.x >> 6;
    if ((threadIdx.x & 63) == 0) {
        red[0][wv] = s0; red[1][wv] = s1; red[2][wv] = q0; red[3][wv] = q1;
    }
    __syncthreads();
    if (threadIdx.x < 4) {
        int i = threadIdx.x;
        float v = red[i][0] + red[i][1] + red[i][2] + red[i][3];
        unsafeAtomicAdd(&stats2[i], v);
    }
}

// K8: BN2 + sigmoid + softmax epilogue
__global__ __launch_bounds__(256) void k10_head(
        const float* __restrict__ out2, const float* __restrict__ stats2,
        const float* __restrict__ g2, const float* __restrict__ beta2,
        float* __restrict__ out) {
    int r = blockIdx.x * blockDim.x + threadIdx.x;
    if (r >= N_NODES) return;
    float invn = 1.f / (float)N_NODES;
    float m0 = stats2[0] * invn, m1 = stats2[1] * invn;
    float v0 = stats2[2] * invn - m0 * m0;
    float v1 = stats2[3] * invn - m1 * m1;
    float i0 = rsqrtf(v0 + BN_EPS), i1 = rsqrtf(v1 + BN_EPS);
    float sc0 = g2[0] * i0, sc1 = g2[1] * i1;
    float sh0 = beta2[0] - m0 * sc0, sh1 = beta2[1] - m1 * sc1;
    float2 x = ((const float2*)out2)[r];
    float y0 = fmaf(x.x, sc0, sh0), y1 = fmaf(x.y, sc1, sh1);
    out[r * 2] = 1.f / (1.f + __expf(-y0));
    out[r * 2 + 1] = 1.f / (1.f + __expf(-y1));
    out[2 * N_NODES + r * 2] = 1.f / (1.f + __expf(y1 - y0));
    out[2 * N_NODES + r * 2 + 1] = 1.f / (1.f + __expf(y0 - y1));
}

extern "C" void kernel_launch(void* const* d_in, const int* in_sizes, int n_in,
                              void* d_out, int out_size, void* d_ws, size_t ws_size,
                              hipStream_t stream) {
    const int*   edge  = (const int*)d_in[0];          // (2,E): [0,E)=src, [E,2E)=dst
    const float* u_S   = (const float*)d_in[1];
    const float* w1    = (const float*)d_in[2];
    const float* g1    = (const float*)d_in[4];
    const float* beta1 = (const float*)d_in[5];
    const float* w2    = (const float*)d_in[6];
    const float* g2    = (const float*)d_in[8];
    const float* beta2 = (const float*)d_in[9];
    float* out = (float*)d_out;

    float*  ws     = (float*)d_ws;
    int*    gcur   = (int*)(ws + OFF_GCUR);
    int*    cnt    = (int*)(ws + OFF_CNT);
    float*  dinv   = ws + OFF_DINV;
    int*    offs   = (int*)(ws + OFF_OFFS);
    int*    ebuf   = (int*)(ws + OFF_EBUF);
    float*  stats1 = ws + OFF_STATS1;
    float*  stats2 = ws + OFF_STATS2;
    __half* hs1    = (__half*)(ws + OFF_HS1);
    int*    binned = (int*)(ws + OFF_BINNED);   // alias of hs1 head; dead before k3_xw1
    __half* out1   = (__half*)(ws + OFF_OUT1);
    float*  hs2    = ws + OFF_HS2;
    float*  out2   = ws + OFF_OUT2;

    const int* src = edge;
    const int* dst = edge + N_EDGES;

    k0_init<<<1, 256, 0, stream>>>(gcur, stats1);
    k_bin<<<NBLK_BIN, 256, 0, stream>>>(src, dst, gcur, binned);
    k_csr<<<NBUCK, 256, 0, stream>>>(gcur, binned, cnt, dinv, offs, ebuf);
    k3_xw1<<<(N_NODES / 16 + 3) / 4, 256, 0, stream>>>(u_S, w1, dinv, hs1);
    k_pull1<<<(N_NODES * 16 + 255) / 256, 256, 0, stream>>>(offs, cnt, ebuf, dinv, hs1, out1);
    k5_stats1<<<256, 256, 0, stream>>>(out1, stats1);
    k7_xw2<<<2048, 256, 0, stream>>>(out1, stats1, g1, beta1, w2, dinv, hs2);
    k_pull2<<<(N_NODES + 255) / 256, 256, 0, stream>>>(offs, cnt, ebuf, dinv, hs2, out2, stats2);
    k10_head<<<(N_NODES + 255) / 256, 256, 0, stream>>>(out2, stats2, g2, beta2, out);
}